// Round 1
// baseline (742.678 us; speedup 1.0000x reference)
//
#include <hip/hip_runtime.h>
#include <hip/hip_bf16.h>
#include <math.h>

#define B_   4
#define H_   128
#define W_   128
#define C_   64
#define L_   (H_*W_)        // 16384 per batch
#define NPIX (B_*L_)        // 65536
#define DI_  128
#define NST  16
#define RT   4
#define TCH  64             // scan chunk length
#define NC   (L_/TCH)       // 256 chunks per batch

__device__ __forceinline__ float gelu_f(float x){
    return 0.5f*x*(1.f+erff(x*0.70710678118654752f));
}
__device__ __forceinline__ float silu_f(float x){
    return x/(1.f+__expf(-x));
}
__device__ __forceinline__ float softplus_f(float x){
    return (x>20.f)? x : log1pf(__expf(x));
}

// ---------------- LayerNorm over C=64 (NHWC), wave-per-... 64 lanes per pixel
__global__ void k_ln(const float* __restrict__ x, const float* __restrict__ g,
                     const float* __restrict__ b, float* __restrict__ xn){
    int tid = threadIdx.x;
    int lane = tid & 63;
    int p = blockIdx.x*4 + (tid>>6);
    float v = x[p*64 + lane];
    float s = v, s2 = v*v;
    #pragma unroll
    for (int off=32; off; off>>=1){
        s  += __shfl_xor(s,  off, 64);
        s2 += __shfl_xor(s2, off, 64);
    }
    float mu  = s*(1.f/64.f);
    float var = s2*(1.f/64.f) - mu*mu;
    float r = rsqrtf(var + 1e-5f);
    xn[p*64+lane] = (v-mu)*r*g[lane] + b[lane];
}

// ---------------- pointwise 64x64: out[p,o] = sum_c in[p,c]*W[o,c]
__global__ void k_pw(const float* __restrict__ in, const float* __restrict__ W,
                     float* __restrict__ out){
    __shared__ float Wl[64*64];    // Wl[c*64+o] = W[o*64+c]
    __shared__ float xl[16*64];
    int tid = threadIdx.x;
    for (int i=tid;i<4096;i+=256){ int o=i>>6, c=i&63; Wl[c*64+o]=W[i]; }
    int base = blockIdx.x*16*64;
    for (int i=tid;i<1024;i+=256) xl[i]=in[base+i];
    __syncthreads();
    int o  = tid&63;
    int pr = tid>>6;
    for (int pp=pr; pp<16; pp+=4){
        float acc=0.f;
        #pragma unroll
        for (int c=0;c<64;c++) acc += xl[pp*64+c]*Wl[c*64+o];
        out[base + pp*64 + o] = acc;
    }
}

// ---------------- depthwise 3x3 SAME (NHWC), optional exact-GELU, optional residual add
template<bool GELU, bool ADDRES>
__global__ void k_dw3(const float* __restrict__ in, const float* __restrict__ w9,
                      const float* __restrict__ res, float* __restrict__ out){
    int idx = blockIdx.x*256 + threadIdx.x;   // over NPIX*64
    int c = idx & 63;
    int p = idx >> 6;
    int j = p & (W_-1);
    int t = p >> 7;       // b*H + i   (W_=128)
    int i = t & (H_-1);
    int b = t >> 7;       // H_=128
    float acc = 0.f;
    #pragma unroll
    for (int ki=0;ki<3;ki++){
        int ii = i + ki - 1;
        if (ii<0||ii>=H_) continue;
        #pragma unroll
        for (int kj=0;kj<3;kj++){
            int jj = j + kj - 1;
            if (jj<0||jj>=W_) continue;
            acc += in[(((b*H_+ii)*W_+jj)<<6)+c]*w9[c*9+ki*3+kj];
        }
    }
    if (GELU)   acc = gelu_f(acc);
    if (ADDRES) acc += res[idx];
    out[idx] = acc;
}

// ---------------- in-projection: xz[p,:256] = x0[p,:64] @ W^T, split xs/z
__global__ void k_inproj(const float* __restrict__ x0, const float* __restrict__ W,
                         float* __restrict__ xs, float* __restrict__ z){
    __shared__ float Wl[64*256];   // Wl[c*256+o] = W[o*64+c]
    __shared__ float xl[32*64];
    int tid=threadIdx.x;
    for (int i=tid;i<16384;i+=256){ int o=i>>6, c=i&63; Wl[c*256+o]=W[i]; }
    int pbase = blockIdx.x*32;
    for (int i=tid;i<2048;i+=256) xl[i]=x0[pbase*64+i];
    __syncthreads();
    int o=tid;
    for (int pp=0;pp<32;pp++){
        float acc=0.f;
        #pragma unroll
        for (int c=0;c<64;c++) acc += xl[pp*64+c]*Wl[c*256+o];
        int gp = pbase+pp;
        if (o<DI_) xs[(size_t)gp*DI_ + o]=acc;
        else       z [(size_t)gp*DI_ + (o-DI_)]=acc;
    }
}

// ---------------- causal depthwise conv1d (k=4) along L + SiLU
__global__ void k_conv(const float* __restrict__ xs, const float* __restrict__ cw,
                       const float* __restrict__ cb, float* __restrict__ u){
    int idx = blockIdx.x*256+threadIdx.x;   // NPIX*128
    int c = idx & 127;
    int t = idx >> 7;      // b*L + l
    int l = t & (L_-1);
    float acc = cb[c];
    #pragma unroll
    for (int k=0;k<4;k++){
        int ll = l + k - 3;
        if (ll>=0) acc += xs[idx + (k-3)*DI_]*cw[c*4+k];
    }
    u[idx]=silu_f(acc);
}

// ---------------- x_dbl = u @ W_xproj^T (36), dt = softplus(dt_r @ W_dt^T + b_dt)
__global__ void k_xproj(const float* __restrict__ u, const float* __restrict__ Wx,
                        const float* __restrict__ Wdt, const float* __restrict__ bdt,
                        float* __restrict__ dt, float* __restrict__ Bm, float* __restrict__ Cm){
    __shared__ float Wxl[36*132];
    __shared__ float ul[8*132];
    __shared__ float dtr[8*4];
    int tid=threadIdx.x;   // 128
    for (int i=tid;i<36*128;i+=128){ int j=i>>7, d=i&127; Wxl[j*132+d]=Wx[i]; }
    int pbase=blockIdx.x*8;
    for (int i=tid;i<1024;i+=128){ int p=i>>7, d=i&127; ul[p*132+d]=u[(size_t)pbase*DI_+i]; }
    __syncthreads();
    for (int it=0; it<3; it++){
        int item = it*128+tid;
        if (item<288){
            int p=item/36, j=item-36*p;
            float acc=0.f;
            #pragma unroll
            for (int d=0;d<128;d++) acc += ul[p*132+d]*Wxl[j*132+d];
            int gp=pbase+p;
            if (j<RT)          dtr[p*4+j]=acc;
            else if (j<RT+NST) Bm[(size_t)gp*NST + (j-RT)]=acc;
            else               Cm[(size_t)gp*NST + (j-RT-NST)]=acc;
        }
    }
    __syncthreads();
    int d=tid;
    float w0=Wdt[d*4+0], w1=Wdt[d*4+1], w2=Wdt[d*4+2], w3=Wdt[d*4+3];
    float bd=bdt[d];
    for (int p=0;p<8;p++){
        float acc = bd + dtr[p*4+0]*w0 + dtr[p*4+1]*w1 + dtr[p*4+2]*w2 + dtr[p*4+3]*w3;
        dt[(size_t)(pbase+p)*DI_+d]=softplus_f(acc);
    }
}

// ---------------- scan pass A: per-chunk local scan (h0=0) -> E, sum(dt)
__global__ void k_scanA(const float* __restrict__ dt, const float* __restrict__ u,
                        const float* __restrict__ Bm, const float* __restrict__ Alog,
                        float* __restrict__ E, float* __restrict__ sumdt){
    __shared__ float Bl[TCH*NST];
    int tid=threadIdx.x;       // = d (128)
    int blk=blockIdx.x;        // b*NC + k
    int b = blk >> 8;          // NC=256
    int k = blk & 255;
    int l0 = k*TCH;
    for (int i=tid;i<TCH*NST;i+=128) Bl[i]=Bm[((size_t)b*L_+l0)*NST+i];
    __syncthreads();
    int d=tid;
    float A[NST], h[NST];
    #pragma unroll
    for (int s=0;s<NST;s++){ A[s] = -__expf(Alog[d*NST+s]); h[s]=0.f; }
    float sd=0.f;
    const float* dtp = dt + ((size_t)b*L_+l0)*DI_ + d;
    const float* up  = u  + ((size_t)b*L_+l0)*DI_ + d;
    for (int t=0;t<TCH;t++){
        float dtv = dtp[t*DI_];
        float uv  = up[t*DI_];
        sd += dtv;
        float du = dtv*uv;
        #pragma unroll
        for (int s=0;s<NST;s++){
            float dA = __expf(dtv*A[s]);
            h[s] = dA*h[s] + du*Bl[t*NST+s];
        }
    }
    size_t eb = ((size_t)blk*DI_ + d)*NST;
    #pragma unroll
    for (int s=0;s<NST;s++) E[eb+s]=h[s];
    sumdt[(size_t)blk*DI_+d]=sd;
}

// ---------------- scan pass B: chunk-level recurrence -> start state per chunk
__global__ void k_scanB(const float* __restrict__ E, const float* __restrict__ sumdt,
                        const float* __restrict__ Alog, float* __restrict__ Hst){
    int idx = blockIdx.x*256+threadIdx.x;  // B*DI*NST = 8192
    if (idx >= B_*DI_*NST) return;
    int s = idx & 15;
    int d = (idx>>4) & 127;
    int b = idx >> 11;
    float Av = -__expf(Alog[d*NST+s]);
    float h = 0.f;
    #pragma unroll 4
    for (int k=0;k<NC;k++){
        size_t base = ((size_t)(b*NC+k)*DI_+d);
        Hst[base*NST+s] = h;
        float P = __expf(Av * sumdt[base]);
        h = P*h + E[base*NST+s];
    }
}

// ---------------- scan pass C: within-chunk scan from true start state -> y
__global__ void k_scanC(const float* __restrict__ dt, const float* __restrict__ u,
                        const float* __restrict__ Bm, const float* __restrict__ Cm,
                        const float* __restrict__ Alog, const float* __restrict__ Hst,
                        float* __restrict__ y){
    __shared__ float Bl[TCH*NST];
    __shared__ float Cl[TCH*NST];
    int tid=threadIdx.x;
    int blk=blockIdx.x;
    int b = blk >> 8;
    int k = blk & 255;
    int l0 = k*TCH;
    for (int i=tid;i<TCH*NST;i+=128){
        Bl[i]=Bm[((size_t)b*L_+l0)*NST+i];
        Cl[i]=Cm[((size_t)b*L_+l0)*NST+i];
    }
    __syncthreads();
    int d=tid;
    float A[NST], h[NST];
    size_t hb = ((size_t)blk*DI_ + d)*NST;
    #pragma unroll
    for (int s=0;s<NST;s++){ A[s]=-__expf(Alog[d*NST+s]); h[s]=Hst[hb+s]; }
    const float* dtp = dt + ((size_t)b*L_+l0)*DI_ + d;
    const float* up  = u  + ((size_t)b*L_+l0)*DI_ + d;
    float* yp = y + ((size_t)b*L_+l0)*DI_ + d;
    for (int t=0;t<TCH;t++){
        float dtv = dtp[t*DI_];
        float uv  = up[t*DI_];
        float du = dtv*uv;
        float yv = 0.f;
        #pragma unroll
        for (int s=0;s<NST;s++){
            float dA = __expf(dtv*A[s]);
            h[s] = dA*h[s] + du*Bl[t*NST+s];
            yv += h[s]*Cl[t*NST+s];
        }
        yp[t*DI_] = yv;
    }
}

// ---------------- gate + out-projection + residual: x1 = ((y+u*D)*silu(z)) @ Wout^T + x0
__global__ void k_gate_out(const float* __restrict__ y, const float* __restrict__ u,
                           const float* __restrict__ z, const float* __restrict__ Dv,
                           const float* __restrict__ Wout, const float* __restrict__ x0,
                           float* __restrict__ x1){
    __shared__ float Wl[128*64];   // Wl[d*64+o] = Wout[o*128+d]
    __shared__ float vl[8*128];
    int tid=threadIdx.x;   // 128
    for (int i=tid;i<8192;i+=128){ int o=i>>7, d=i&127; Wl[d*64+o]=Wout[i]; }
    int pbase=blockIdx.x*8;
    int d=tid;
    float Dd = Dv[d];
    for (int p=0;p<8;p++){
        size_t gi=(size_t)(pbase+p)*DI_+d;
        vl[p*128+d] = (y[gi]+u[gi]*Dd)*silu_f(z[gi]);
    }
    __syncthreads();
    int o  = tid&63;
    int ph = tid>>6;    // 0..1
    for (int p=ph;p<8;p+=2){
        float acc=0.f;
        #pragma unroll
        for (int dd=0;dd<128;dd++) acc += vl[p*128+dd]*Wl[dd*64+o];
        size_t gi=(size_t)(pbase+p)*64+o;
        x1[gi]=acc + x0[gi];
    }
}

extern "C" void kernel_launch(void* const* d_in, const int* in_sizes, int n_in,
                              void* d_out, int out_size, void* d_ws, size_t ws_size,
                              hipStream_t stream){
    const float* x      = (const float*)d_in[0];
    const float* ln_g   = (const float*)d_in[1];
    const float* ln_b   = (const float*)d_in[2];
    const float* w_pw1  = (const float*)d_in[3];
    const float* w_dw   = (const float*)d_in[4];
    const float* w_pw2  = (const float*)d_in[5];
    const float* w_odw1 = (const float*)d_in[6];
    const float* w_odw2 = (const float*)d_in[7];
    const float* W_inpj = (const float*)d_in[8];
    const float* conv_w = (const float*)d_in[9];
    const float* conv_b = (const float*)d_in[10];
    const float* W_xprj = (const float*)d_in[11];
    const float* W_dt   = (const float*)d_in[12];
    const float* b_dt   = (const float*)d_in[13];
    const float* A_log  = (const float*)d_in[14];
    const float* Dvec   = (const float*)d_in[15];
    const float* W_out  = (const float*)d_in[16];
    float* out = (float*)d_out;

    char* ws = (char*)d_ws;
    const size_t SZ64  = (size_t)NPIX*64*4;    // 16 MiB
    const size_t SZ128 = (size_t)NPIX*128*4;   // 32 MiB
    // Buffer plan (time-multiplexed; ~192 MiB total):
    //  A1: xn  -> x1
    //  A2: t1  -> {E, sumdt} -> t3
    //  A3: t2  -> {Bm, Cm, Hst}
    //  A4: x0                  A5: xs -> y     A6: z    A7: u    A8: dt
    float* A1 = (float*)(ws);
    float* A2 = (float*)(ws + SZ64);
    float* A3 = (float*)(ws + 2*SZ64);
    float* A4 = (float*)(ws + 3*SZ64);
    float* A5 = (float*)(ws + 4*SZ64);
    float* A6 = (float*)(ws + 4*SZ64 + SZ128);
    float* A7 = (float*)(ws + 4*SZ64 + 2*SZ128);
    float* A8 = (float*)(ws + 4*SZ64 + 3*SZ128);
    float* Ebuf  = A2;
    float* sumdt = (float*)((char*)A2 + (size_t)B_*NC*DI_*NST*4);
    float* Bmb = A3;
    float* Cmb = (float*)((char*)A3 + (size_t)NPIX*NST*4);
    float* Hst = (float*)((char*)A3 + (size_t)2*NPIX*NST*4);

    k_ln            <<<NPIX/4,      256, 0, stream>>>(x, ln_g, ln_b, A1);
    k_pw            <<<NPIX/16,     256, 0, stream>>>(A1, w_pw1, A2);
    k_dw3<true,false><<<NPIX*64/256,256, 0, stream>>>(A2, w_dw, nullptr, A3);
    k_pw            <<<NPIX/16,     256, 0, stream>>>(A3, w_pw2, A4);
    k_inproj        <<<NPIX/32,     256, 0, stream>>>(A4, W_inpj, A5, A6);
    k_conv          <<<NPIX*128/256,256, 0, stream>>>(A5, conv_w, conv_b, A7);
    k_xproj         <<<NPIX/8,      128, 0, stream>>>(A7, W_xprj, W_dt, b_dt, A8, Bmb, Cmb);
    k_scanA         <<<B_*NC,       128, 0, stream>>>(A8, A7, Bmb, A_log, Ebuf, sumdt);
    k_scanB         <<<(B_*DI_*NST+255)/256, 256, 0, stream>>>(Ebuf, sumdt, A_log, Hst);
    k_scanC         <<<B_*NC,       128, 0, stream>>>(A8, A7, Bmb, Cmb, A_log, Hst, A5);
    k_gate_out      <<<NPIX/8,      128, 0, stream>>>(A5, A7, A6, Dvec, W_out, A4, A1);
    k_dw3<true,false><<<NPIX*64/256,256, 0, stream>>>(A1, w_odw1, nullptr, A2);
    k_dw3<false,true><<<NPIX*64/256,256, 0, stream>>>(A2, w_odw2, A1, out);
}

// Round 2
// 727.650 us; speedup vs baseline: 1.0207x; 1.0207x over previous
//
#include <hip/hip_runtime.h>
#include <hip/hip_bf16.h>
#include <math.h>

#define B_   4
#define H_   128
#define W_   128
#define C_   64
#define L_   (H_*W_)        // 16384 per batch
#define NPIX (B_*L_)        // 65536
#define DI_  128
#define NST  16
#define RT   4
#define TCH  64             // scan chunk length
#define NC   (L_/TCH)       // 256 chunks per batch

__device__ __forceinline__ float gelu_f(float x){
    return 0.5f*x*(1.f+erff(x*0.70710678118654752f));
}
__device__ __forceinline__ float silu_f(float x){
    return x/(1.f+__expf(-x));
}
__device__ __forceinline__ float softplus_f(float x){
    return (x>20.f)? x : log1pf(__expf(x));
}

// ---------------- LayerNorm over C=64 (NHWC), 64 lanes per pixel
__global__ void k_ln(const float* __restrict__ x, const float* __restrict__ g,
                     const float* __restrict__ b, float* __restrict__ xn){
    int tid = threadIdx.x;
    int lane = tid & 63;
    int p = blockIdx.x*4 + (tid>>6);
    float v = x[p*64 + lane];
    float s = v, s2 = v*v;
    #pragma unroll
    for (int off=32; off; off>>=1){
        s  += __shfl_xor(s,  off, 64);
        s2 += __shfl_xor(s2, off, 64);
    }
    float mu  = s*(1.f/64.f);
    float var = s2*(1.f/64.f) - mu*mu;
    float r = rsqrtf(var + 1e-5f);
    xn[p*64+lane] = (v-mu)*r*g[lane] + b[lane];
}

// ---------------- pointwise 64x64: out[p,o] = sum_c in[p,c]*W[o,c]
// 256 thr, 64 pixels/block. Wl padded stride 65 -> conflict-free write+read.
__global__ void k_pw(const float* __restrict__ in, const float* __restrict__ W,
                     float* __restrict__ out){
    __shared__ float Wl[64*65];    // Wl[c*65+o] = W[o*64+c]
    __shared__ float xl[64*64];
    int tid = threadIdx.x;
    for (int i=tid;i<4096;i+=256){ int o=i>>6, c=i&63; Wl[c*65+o]=W[i]; }
    size_t base = (size_t)blockIdx.x*64*64;
    for (int i=tid;i<4096;i+=256) xl[i]=in[base+i];
    __syncthreads();
    int o  = tid&63;
    int pr = tid>>6;                // 0..3
    for (int pp=pr; pp<64; pp+=4){
        float acc=0.f;
        #pragma unroll
        for (int c=0;c<64;c++) acc += xl[pp*64+c]*Wl[c*65+o];
        out[base + pp*64 + o] = acc;
    }
}

// ---------------- depthwise 3x3 SAME (NHWC), optional exact-GELU, optional residual add
template<bool GELU, bool ADDRES>
__global__ void k_dw3(const float* __restrict__ in, const float* __restrict__ w9,
                      const float* __restrict__ res, float* __restrict__ out){
    int idx = blockIdx.x*256 + threadIdx.x;   // over NPIX*64
    int c = idx & 63;
    int p = idx >> 6;
    int j = p & (W_-1);
    int t = p >> 7;       // b*H + i   (W_=128)
    int i = t & (H_-1);
    int b = t >> 7;       // H_=128
    float acc = 0.f;
    #pragma unroll
    for (int ki=0;ki<3;ki++){
        int ii = i + ki - 1;
        if (ii<0||ii>=H_) continue;
        #pragma unroll
        for (int kj=0;kj<3;kj++){
            int jj = j + kj - 1;
            if (jj<0||jj>=W_) continue;
            acc += in[(((b*H_+ii)*W_+jj)<<6)+c]*w9[c*9+ki*3+kj];
        }
    }
    if (GELU)   acc = gelu_f(acc);
    if (ADDRES) acc += res[idx];
    out[idx] = acc;
}

// ---------------- in-projection: xz[p,:256] = x0[p,:64] @ W^T, split xs/z
// 256 thr, 32 pixels/block. Wl padded stride 257.
__global__ void k_inproj(const float* __restrict__ x0, const float* __restrict__ W,
                         float* __restrict__ xs, float* __restrict__ z){
    __shared__ float Wl[64*257];   // Wl[c*257+o] = W[o*64+c]
    __shared__ float xl[32*64];
    int tid=threadIdx.x;
    for (int i=tid;i<16384;i+=256){ int o=i>>6, c=i&63; Wl[c*257+o]=W[i]; }
    size_t pbase = (size_t)blockIdx.x*32;
    for (int i=tid;i<2048;i+=256) xl[i]=x0[pbase*64+i];
    __syncthreads();
    int o=tid;
    for (int pp=0;pp<32;pp++){
        float acc=0.f;
        #pragma unroll
        for (int c=0;c<64;c++) acc += xl[pp*64+c]*Wl[c*257+o];
        size_t gp = pbase+pp;
        if (o<DI_) xs[gp*DI_ + o]=acc;
        else       z [gp*DI_ + (o-DI_)]=acc;
    }
}

// ---------------- causal depthwise conv1d (k=4) along L + SiLU
__global__ void k_conv(const float* __restrict__ xs, const float* __restrict__ cw,
                       const float* __restrict__ cb, float* __restrict__ u){
    int idx = blockIdx.x*256+threadIdx.x;   // NPIX*128
    int c = idx & 127;
    int t = idx >> 7;      // b*L + l
    int l = t & (L_-1);
    float acc = cb[c];
    #pragma unroll
    for (int k=0;k<4;k++){
        int ll = l + k - 3;
        if (ll>=0) acc += xs[idx + (k-3)*DI_]*cw[c*4+k];
    }
    u[idx]=silu_f(acc);
}

// ---------------- x_dbl = u @ W_xproj^T (36), dt = softplus(dt_r @ W_dt^T + b_dt)
__global__ void k_xproj(const float* __restrict__ u, const float* __restrict__ Wx,
                        const float* __restrict__ Wdt, const float* __restrict__ bdt,
                        float* __restrict__ dt, float* __restrict__ Bm, float* __restrict__ Cm){
    __shared__ float Wxl[36*133];
    __shared__ float ul[8*133];
    __shared__ float dtr[8*4];
    int tid=threadIdx.x;   // 128
    for (int i=tid;i<36*128;i+=128){ int j=i>>7, d=i&127; Wxl[j*133+d]=Wx[i]; }
    int pbase=blockIdx.x*8;
    for (int i=tid;i<1024;i+=128){ int p=i>>7, d=i&127; ul[p*133+d]=u[(size_t)pbase*DI_+i]; }
    __syncthreads();
    for (int it=0; it<3; it++){
        int item = it*128+tid;
        if (item<288){
            int p=item/36, j=item-36*p;
            float acc=0.f;
            #pragma unroll
            for (int d=0;d<128;d++) acc += ul[p*133+d]*Wxl[j*133+d];
            int gp=pbase+p;
            if (j<RT)          dtr[p*4+j]=acc;
            else if (j<RT+NST) Bm[(size_t)gp*NST + (j-RT)]=acc;
            else               Cm[(size_t)gp*NST + (j-RT-NST)]=acc;
        }
    }
    __syncthreads();
    int d=tid;
    float w0=Wdt[d*4+0], w1=Wdt[d*4+1], w2=Wdt[d*4+2], w3=Wdt[d*4+3];
    float bd=bdt[d];
    for (int p=0;p<8;p++){
        float acc = bd + dtr[p*4+0]*w0 + dtr[p*4+1]*w1 + dtr[p*4+2]*w2 + dtr[p*4+3]*w3;
        dt[(size_t)(pbase+p)*DI_+d]=softplus_f(acc);
    }
}

// ---------------- scan pass A: per-chunk local scan (h0=0) -> E, sum(dt)
__global__ void k_scanA(const float* __restrict__ dt, const float* __restrict__ u,
                        const float* __restrict__ Bm, const float* __restrict__ Alog,
                        float* __restrict__ E, float* __restrict__ sumdt){
    __shared__ float Bl[TCH*NST];
    int tid=threadIdx.x;       // = d (128)
    int blk=blockIdx.x;        // b*NC + k
    int b = blk >> 8;          // NC=256
    int k = blk & 255;
    int l0 = k*TCH;
    for (int i=tid;i<TCH*NST;i+=128) Bl[i]=Bm[((size_t)b*L_+l0)*NST+i];
    __syncthreads();
    int d=tid;
    float A[NST], h[NST];
    #pragma unroll
    for (int s=0;s<NST;s++){ A[s] = -__expf(Alog[d*NST+s]); h[s]=0.f; }
    float sd=0.f;
    const float* dtp = dt + ((size_t)b*L_+l0)*DI_ + d;
    const float* up  = u  + ((size_t)b*L_+l0)*DI_ + d;
    for (int t=0;t<TCH;t++){
        float dtv = dtp[t*DI_];
        float uv  = up[t*DI_];
        sd += dtv;
        float du = dtv*uv;
        #pragma unroll
        for (int s=0;s<NST;s++){
            float dA = __expf(dtv*A[s]);
            h[s] = dA*h[s] + du*Bl[t*NST+s];
        }
    }
    size_t eb = ((size_t)blk*DI_ + d)*NST;
    #pragma unroll
    for (int s=0;s<NST;s++) E[eb+s]=h[s];
    sumdt[(size_t)blk*DI_+d]=sd;
}

// ---------------- scan pass B: chunk-level recurrence -> start state per chunk
__global__ void k_scanB(const float* __restrict__ E, const float* __restrict__ sumdt,
                        const float* __restrict__ Alog, float* __restrict__ Hst){
    int idx = blockIdx.x*256+threadIdx.x;  // B*DI*NST = 8192
    if (idx >= B_*DI_*NST) return;
    int s = idx & 15;
    int d = (idx>>4) & 127;
    int b = idx >> 11;
    float Av = -__expf(Alog[d*NST+s]);
    float h = 0.f;
    #pragma unroll 4
    for (int k=0;k<NC;k++){
        size_t base = ((size_t)(b*NC+k)*DI_+d);
        Hst[base*NST+s] = h;
        float P = __expf(Av * sumdt[base]);
        h = P*h + E[base*NST+s];
    }
}

// ---------------- scan pass C: within-chunk scan from true start state -> y
__global__ void k_scanC(const float* __restrict__ dt, const float* __restrict__ u,
                        const float* __restrict__ Bm, const float* __restrict__ Cm,
                        const float* __restrict__ Alog, const float* __restrict__ Hst,
                        float* __restrict__ y){
    __shared__ float Bl[TCH*NST];
    __shared__ float Cl[TCH*NST];
    int tid=threadIdx.x;
    int blk=blockIdx.x;
    int b = blk >> 8;
    int k = blk & 255;
    int l0 = k*TCH;
    for (int i=tid;i<TCH*NST;i+=128){
        Bl[i]=Bm[((size_t)b*L_+l0)*NST+i];
        Cl[i]=Cm[((size_t)b*L_+l0)*NST+i];
    }
    __syncthreads();
    int d=tid;
    float A[NST], h[NST];
    size_t hb = ((size_t)blk*DI_ + d)*NST;
    #pragma unroll
    for (int s=0;s<NST;s++){ A[s]=-__expf(Alog[d*NST+s]); h[s]=Hst[hb+s]; }
    const float* dtp = dt + ((size_t)b*L_+l0)*DI_ + d;
    const float* up  = u  + ((size_t)b*L_+l0)*DI_ + d;
    float* yp = y + ((size_t)b*L_+l0)*DI_ + d;
    for (int t=0;t<TCH;t++){
        float dtv = dtp[t*DI_];
        float uv  = up[t*DI_];
        float du = dtv*uv;
        float yv = 0.f;
        #pragma unroll
        for (int s=0;s<NST;s++){
            float dA = __expf(dtv*A[s]);
            h[s] = dA*h[s] + du*Bl[t*NST+s];
            yv += h[s]*Cl[t*NST+s];
        }
        yp[t*DI_] = yv;
    }
}

// ---------------- gate + out-projection + residual: x1 = ((y+u*D)*silu(z)) @ Wout^T + x0
// 256 thr, 32 pixels/block. Wl padded stride 65.
__global__ void k_gate_out(const float* __restrict__ y, const float* __restrict__ u,
                           const float* __restrict__ z, const float* __restrict__ Dv,
                           const float* __restrict__ Wout, const float* __restrict__ x0,
                           float* __restrict__ x1){
    __shared__ float Wl[128*65];   // Wl[d*65+o] = Wout[o*128+d]
    __shared__ float vl[32*128];
    int tid=threadIdx.x;   // 256
    for (int i=tid;i<8192;i+=256){ int o=i>>7, d=i&127; Wl[d*65+o]=Wout[i]; }
    size_t pbase=(size_t)blockIdx.x*32;
    int d  = tid&127;
    int ph = tid>>7;       // 0..1
    float Dd = Dv[d];
    for (int p=ph;p<32;p+=2){
        size_t gi=(pbase+p)*DI_+d;
        vl[p*128+d] = (y[gi]+u[gi]*Dd)*silu_f(z[gi]);
    }
    __syncthreads();
    int o  = tid&63;
    int pr = tid>>6;       // 0..3
    for (int p=pr;p<32;p+=4){
        float acc=0.f;
        #pragma unroll
        for (int dd=0;dd<128;dd++) acc += vl[p*128+dd]*Wl[dd*65+o];
        size_t gi=(pbase+p)*64+o;
        x1[gi]=acc + x0[gi];
    }
}

extern "C" void kernel_launch(void* const* d_in, const int* in_sizes, int n_in,
                              void* d_out, int out_size, void* d_ws, size_t ws_size,
                              hipStream_t stream){
    const float* x      = (const float*)d_in[0];
    const float* ln_g   = (const float*)d_in[1];
    const float* ln_b   = (const float*)d_in[2];
    const float* w_pw1  = (const float*)d_in[3];
    const float* w_dw   = (const float*)d_in[4];
    const float* w_pw2  = (const float*)d_in[5];
    const float* w_odw1 = (const float*)d_in[6];
    const float* w_odw2 = (const float*)d_in[7];
    const float* W_inpj = (const float*)d_in[8];
    const float* conv_w = (const float*)d_in[9];
    const float* conv_b = (const float*)d_in[10];
    const float* W_xprj = (const float*)d_in[11];
    const float* W_dt   = (const float*)d_in[12];
    const float* b_dt   = (const float*)d_in[13];
    const float* A_log  = (const float*)d_in[14];
    const float* Dvec   = (const float*)d_in[15];
    const float* W_out  = (const float*)d_in[16];
    float* out = (float*)d_out;

    char* ws = (char*)d_ws;
    const size_t SZ64  = (size_t)NPIX*64*4;    // 16 MiB
    const size_t SZ128 = (size_t)NPIX*128*4;   // 32 MiB
    float* A1 = (float*)(ws);
    float* A2 = (float*)(ws + SZ64);
    float* A3 = (float*)(ws + 2*SZ64);
    float* A4 = (float*)(ws + 3*SZ64);
    float* A5 = (float*)(ws + 4*SZ64);
    float* A6 = (float*)(ws + 4*SZ64 + SZ128);
    float* A7 = (float*)(ws + 4*SZ64 + 2*SZ128);
    float* A8 = (float*)(ws + 4*SZ64 + 3*SZ128);
    float* Ebuf  = A2;
    float* sumdt = (float*)((char*)A2 + (size_t)B_*NC*DI_*NST*4);
    float* Bmb = A3;
    float* Cmb = (float*)((char*)A3 + (size_t)NPIX*NST*4);
    float* Hst = (float*)((char*)A3 + (size_t)2*NPIX*NST*4);

    k_ln            <<<NPIX/4,      256, 0, stream>>>(x, ln_g, ln_b, A1);
    k_pw            <<<NPIX/64,     256, 0, stream>>>(A1, w_pw1, A2);
    k_dw3<true,false><<<NPIX*64/256,256, 0, stream>>>(A2, w_dw, nullptr, A3);
    k_pw            <<<NPIX/64,     256, 0, stream>>>(A3, w_pw2, A4);
    k_inproj        <<<NPIX/32,     256, 0, stream>>>(A4, W_inpj, A5, A6);
    k_conv          <<<NPIX*128/256,256, 0, stream>>>(A5, conv_w, conv_b, A7);
    k_xproj         <<<NPIX/8,      128, 0, stream>>>(A7, W_xprj, W_dt, b_dt, A8, Bmb, Cmb);
    k_scanA         <<<B_*NC,       128, 0, stream>>>(A8, A7, Bmb, A_log, Ebuf, sumdt);
    k_scanB         <<<(B_*DI_*NST+255)/256, 256, 0, stream>>>(Ebuf, sumdt, A_log, Hst);
    k_scanC         <<<B_*NC,       128, 0, stream>>>(A8, A7, Bmb, Cmb, A_log, Hst, A5);
    k_gate_out      <<<NPIX/32,     128+128, 0, stream>>>(A5, A7, A6, Dvec, W_out, A4, A1);
    k_dw3<true,false><<<NPIX*64/256,256, 0, stream>>>(A1, w_odw1, nullptr, A2);
    k_dw3<false,true><<<NPIX*64/256,256, 0, stream>>>(A2, w_odw2, A1, out);
}

// Round 3
// 529.263 us; speedup vs baseline: 1.4032x; 1.3748x over previous
//
#include <hip/hip_runtime.h>
#include <hip/hip_bf16.h>
#include <math.h>

#define B_   4
#define H_   128
#define W_   128
#define C_   64
#define L_   (H_*W_)        // 16384 per batch
#define NPIX (B_*L_)        // 65536
#define DI_  128
#define NST  16
#define RT   4
#define TCH  64             // scan chunk length
#define NC   (L_/TCH)       // 256 chunks per batch

__device__ __forceinline__ float gelu_f(float x){
    return 0.5f*x*(1.f+erff(x*0.70710678118654752f));
}
__device__ __forceinline__ float silu_f(float x){
    return x/(1.f+__expf(-x));
}
__device__ __forceinline__ float softplus_f(float x){
    return (x>20.f)? x : log1pf(__expf(x));
}

// ---------------- fused LayerNorm + pw1: out[p,o] = sum_c LN(x)[p,c]*W[o,c]
// 256 thr, 64 px/block. Register-tiled 4x4.
__global__ void k_lnpw(const float* __restrict__ x, const float* __restrict__ g,
                       const float* __restrict__ b, const float* __restrict__ W,
                       float* __restrict__ out){
    __shared__ float xl[64*65];
    __shared__ float Wt[64*65];    // Wt[c*65+o] = W[o*64+c]
    int tid = threadIdx.x;
    for (int i=tid;i<4096;i+=256){ int o=i>>6, c=i&63; Wt[c*65+o]=W[i]; }
    size_t base = (size_t)blockIdx.x*64*64;
    int c  = tid&63;
    int pr = tid>>6;
    float gc=g[c], bc=b[c];
    for (int p=pr;p<64;p+=4){
        float v = x[base + p*64 + c];
        float s=v, s2=v*v;
        #pragma unroll
        for (int off=32; off; off>>=1){
            s  += __shfl_xor(s,  off, 64);
            s2 += __shfl_xor(s2, off, 64);
        }
        float mu = s*(1.f/64.f);
        float var= s2*(1.f/64.f) - mu*mu;
        float r  = rsqrtf(var + 1e-5f);
        xl[p*65+c] = (v-mu)*r*gc + bc;
    }
    __syncthreads();
    int og=(tid&15)*4, pg=(tid>>4)*4;
    float acc[4][4]={};
    for (int cc=0;cc<64;cc++){
        float bv[4], av[4];
        #pragma unroll
        for (int j=0;j<4;j++) bv[j]=Wt[cc*65+og+j];
        #pragma unroll
        for (int i=0;i<4;i++) av[i]=xl[(pg+i)*65+cc];
        #pragma unroll
        for (int i=0;i<4;i++)
            #pragma unroll
            for (int j=0;j<4;j++) acc[i][j]+=av[i]*bv[j];
    }
    #pragma unroll
    for (int i=0;i<4;i++){
        float4 v4 = {acc[i][0],acc[i][1],acc[i][2],acc[i][3]};
        *(float4*)(out + base + (pg+i)*64 + og) = v4;
    }
}

// ---------------- pointwise 64x64 (register-tiled 4x4)
__global__ void k_pw(const float* __restrict__ in, const float* __restrict__ W,
                     float* __restrict__ out){
    __shared__ float xl[64*65];
    __shared__ float Wt[64*65];
    int tid = threadIdx.x;
    for (int i=tid;i<4096;i+=256){ int o=i>>6, c=i&63; Wt[c*65+o]=W[i]; }
    size_t base = (size_t)blockIdx.x*64*64;
    for (int i=tid;i<4096;i+=256) xl[(i>>6)*65+(i&63)]=in[base+i];
    __syncthreads();
    int og=(tid&15)*4, pg=(tid>>4)*4;
    float acc[4][4]={};
    for (int cc=0;cc<64;cc++){
        float bv[4], av[4];
        #pragma unroll
        for (int j=0;j<4;j++) bv[j]=Wt[cc*65+og+j];
        #pragma unroll
        for (int i=0;i<4;i++) av[i]=xl[(pg+i)*65+cc];
        #pragma unroll
        for (int i=0;i<4;i++)
            #pragma unroll
            for (int j=0;j<4;j++) acc[i][j]+=av[i]*bv[j];
    }
    #pragma unroll
    for (int i=0;i<4;i++){
        float4 v4 = {acc[i][0],acc[i][1],acc[i][2],acc[i][3]};
        *(float4*)(out + base + (pg+i)*64 + og) = v4;
    }
}

// ---------------- depthwise 3x3 SAME (NHWC), optional exact-GELU, optional residual add
template<bool GELU, bool ADDRES>
__global__ void k_dw3(const float* __restrict__ in, const float* __restrict__ w9,
                      const float* __restrict__ res, float* __restrict__ out){
    int idx = blockIdx.x*256 + threadIdx.x;   // over NPIX*64
    int c = idx & 63;
    int p = idx >> 6;
    int j = p & (W_-1);
    int t = p >> 7;       // b*H + i   (W_=128)
    int i = t & (H_-1);
    int b = t >> 7;       // H_=128
    float acc = 0.f;
    #pragma unroll
    for (int ki=0;ki<3;ki++){
        int ii = i + ki - 1;
        if (ii<0||ii>=H_) continue;
        #pragma unroll
        for (int kj=0;kj<3;kj++){
            int jj = j + kj - 1;
            if (jj<0||jj>=W_) continue;
            acc += in[(((b*H_+ii)*W_+jj)<<6)+c]*w9[c*9+ki*3+kj];
        }
    }
    if (GELU)   acc = gelu_f(acc);
    if (ADDRES) acc += res[idx];
    out[idx] = acc;
}

// ---------------- in-projection: 64 px/block, o-half per blockIdx.y, 8x4 tiles
__global__ void k_inproj(const float* __restrict__ x0, const float* __restrict__ W,
                         float* __restrict__ xs, float* __restrict__ z){
    __shared__ float xl[64*65];
    __shared__ float Wt[64*129];   // Wt[c*129+o'] = Wh[o'*64+c], o' in half
    int tid=threadIdx.x;
    const float* Wh = W + (size_t)blockIdx.y*128*64;
    for (int i=tid;i<8192;i+=256){ int o=i>>6, c=i&63; Wt[c*129+o]=Wh[i]; }
    size_t base=(size_t)blockIdx.x*64*64;
    for (int i=tid;i<4096;i+=256) xl[(i>>6)*65+(i&63)]=x0[base+i];
    __syncthreads();
    int og=(tid>>3)*4;    // 0..124
    int pg=(tid&7)*8;     // 0..56
    float acc[8][4]={};
    for (int cc=0;cc<64;cc++){
        float bv[4];
        #pragma unroll
        for (int j=0;j<4;j++) bv[j]=Wt[cc*129+og+j];
        #pragma unroll
        for (int i=0;i<8;i++){
            float av=xl[(pg+i)*65+cc];
            #pragma unroll
            for (int j=0;j<4;j++) acc[i][j]+=av*bv[j];
        }
    }
    size_t prow=(size_t)blockIdx.x*64;
    float* dst = blockIdx.y ? z : xs;
    #pragma unroll
    for (int i=0;i<8;i++){
        float4 v4={acc[i][0],acc[i][1],acc[i][2],acc[i][3]};
        *(float4*)(dst + (prow+pg+i)*DI_ + og) = v4;
    }
}

// ---------------- causal depthwise conv1d (k=4) along L + SiLU
__global__ void k_conv(const float* __restrict__ xs, const float* __restrict__ cw,
                       const float* __restrict__ cb, float* __restrict__ u){
    int idx = blockIdx.x*256+threadIdx.x;   // NPIX*128
    int c = idx & 127;
    int t = idx >> 7;      // b*L + l
    int l = t & (L_-1);
    float acc = cb[c];
    #pragma unroll
    for (int k=0;k<4;k++){
        int ll = l + k - 3;
        if (ll>=0) acc += xs[idx + (k-3)*DI_]*cw[c*4+k];
    }
    u[idx]=silu_f(acc);
}

// ---------------- x_dbl = u @ W_xproj^T (36) [float4 k-loop], dt = softplus(dt_r @ W_dt^T + b_dt)
__global__ void k_xproj(const float* __restrict__ u, const float* __restrict__ Wx,
                        const float* __restrict__ Wdt, const float* __restrict__ bdt,
                        float* __restrict__ dt, float* __restrict__ Bm, float* __restrict__ Cm){
    __shared__ float Wxl[36*132];
    __shared__ float ul[8*132];
    __shared__ float sB[8*16];
    __shared__ float sC[8*16];
    __shared__ float dtr[8*4];
    int tid=threadIdx.x;   // 128
    for (int i=tid;i<36*128;i+=128){ int j=i>>7, d=i&127; Wxl[j*132+d]=Wx[i]; }
    int pbase=blockIdx.x*8;
    for (int i=tid;i<1024;i+=128){ int p=i>>7, d=i&127; ul[p*132+d]=u[(size_t)pbase*DI_+i]; }
    __syncthreads();
    for (int it=0; it<3; it++){
        int item = it*128+tid;
        if (item<288){
            int p=item/36, j=item-36*p;
            const float4* a4=(const float4*)(ul + p*132);
            const float4* w4=(const float4*)(Wxl + j*132);
            float4 av={0,0,0,0};
            #pragma unroll 8
            for (int d4=0; d4<32; d4++){
                float4 a=a4[d4], w=w4[d4];
                av.x+=a.x*w.x; av.y+=a.y*w.y; av.z+=a.z*w.z; av.w+=a.w*w.w;
            }
            float acc=av.x+av.y+av.z+av.w;
            if (j<RT)          dtr[p*4+j]=acc;
            else if (j<RT+NST) sB[p*16 + (j-RT)]=acc;
            else               sC[p*16 + (j-RT-NST)]=acc;
        }
    }
    __syncthreads();
    // coalesced copy-out of B/C
    {
        int p=tid>>4, s=tid&15;
        Bm[(size_t)(pbase+p)*NST + s] = sB[p*16+s];
        Cm[(size_t)(pbase+p)*NST + s] = sC[p*16+s];
    }
    int d=tid;
    float w0=Wdt[d*4+0], w1=Wdt[d*4+1], w2=Wdt[d*4+2], w3=Wdt[d*4+3];
    float bd=bdt[d];
    for (int p=0;p<8;p++){
        float acc = bd + dtr[p*4+0]*w0 + dtr[p*4+1]*w1 + dtr[p*4+2]*w2 + dtr[p*4+3]*w3;
        dt[(size_t)(pbase+p)*DI_+d]=softplus_f(acc);
    }
}

// ---------------- scan pass A: per-chunk local scan (h0=0) -> E, sum(dt)
__global__ void k_scanA(const float* __restrict__ dt, const float* __restrict__ u,
                        const float* __restrict__ Bm, const float* __restrict__ Alog,
                        float* __restrict__ E, float* __restrict__ sumdt){
    __shared__ float Bl[TCH*NST];
    int tid=threadIdx.x;       // = d (128)
    int blk=blockIdx.x;        // b*NC + k
    int b = blk >> 8;          // NC=256
    int k = blk & 255;
    int l0 = k*TCH;
    for (int i=tid;i<TCH*NST;i+=128) Bl[i]=Bm[((size_t)b*L_+l0)*NST+i];
    __syncthreads();
    int d=tid;
    float A[NST], h[NST];
    #pragma unroll
    for (int s=0;s<NST;s++){ A[s] = -__expf(Alog[d*NST+s]); h[s]=0.f; }
    float sd=0.f;
    const float* dtp = dt + ((size_t)b*L_+l0)*DI_ + d;
    const float* up  = u  + ((size_t)b*L_+l0)*DI_ + d;
    for (int t=0;t<TCH;t++){
        float dtv = dtp[t*DI_];
        float uv  = up[t*DI_];
        sd += dtv;
        float du = dtv*uv;
        #pragma unroll
        for (int s=0;s<NST;s++){
            float dA = __expf(dtv*A[s]);
            h[s] = dA*h[s] + du*Bl[t*NST+s];
        }
    }
    size_t eb = ((size_t)blk*DI_ + d)*NST;
    #pragma unroll
    for (int s=0;s<NST;s++) E[eb+s]=h[s];
    sumdt[(size_t)blk*DI_+d]=sd;
}

// ---------------- scan pass B: chunk-level recurrence -> start state per chunk
__global__ void k_scanB(const float* __restrict__ E, const float* __restrict__ sumdt,
                        const float* __restrict__ Alog, float* __restrict__ Hst){
    int idx = blockIdx.x*256+threadIdx.x;  // B*DI*NST = 8192
    if (idx >= B_*DI_*NST) return;
    int s = idx & 15;
    int d = (idx>>4) & 127;
    int b = idx >> 11;
    float Av = -__expf(Alog[d*NST+s]);
    float h = 0.f;
    #pragma unroll 4
    for (int k=0;k<NC;k++){
        size_t base = ((size_t)(b*NC+k)*DI_+d);
        Hst[base*NST+s] = h;
        float P = __expf(Av * sumdt[base]);
        h = P*h + E[base*NST+s];
    }
}

// ---------------- scan pass C fused with gate + out-projection + residual:
// x1 = ((y + u*D) * silu(z)) @ Wout^T + x0
__global__ void k_scanC_gate(const float* __restrict__ dt, const float* __restrict__ u,
                             const float* __restrict__ Bm, const float* __restrict__ Cm,
                             const float* __restrict__ Alog, const float* __restrict__ Hst,
                             const float* __restrict__ z, const float* __restrict__ Dv,
                             const float* __restrict__ Wout, const float* __restrict__ x0,
                             float* __restrict__ x1){
    __shared__ float Bl[TCH*NST];
    __shared__ float Cl[TCH*NST];
    __shared__ float vl[TCH*129];   // gated value, [t][d] padded
    __shared__ float Wl[128*65];    // Wl[d*65+o] = Wout[o*128+d]
    int tid=threadIdx.x;   // 128
    int blk=blockIdx.x;
    int b = blk >> 8;
    int k = blk & 255;
    int l0 = k*TCH;
    for (int i=tid;i<TCH*NST;i+=128){
        Bl[i]=Bm[((size_t)b*L_+l0)*NST+i];
        Cl[i]=Cm[((size_t)b*L_+l0)*NST+i];
    }
    for (int i=tid;i<8192;i+=128){ int o=i>>7, d=i&127; Wl[d*65+o]=Wout[i]; }
    __syncthreads();
    int d=tid;
    float A[NST], h[NST];
    size_t hb = ((size_t)blk*DI_ + d)*NST;
    #pragma unroll
    for (int s=0;s<NST;s++){ A[s]=-__expf(Alog[d*NST+s]); h[s]=Hst[hb+s]; }
    const float* dtp = dt + ((size_t)b*L_+l0)*DI_ + d;
    const float* up  = u  + ((size_t)b*L_+l0)*DI_ + d;
    const float* zp  = z  + ((size_t)b*L_+l0)*DI_ + d;
    float Dd = Dv[d];
    for (int t=0;t<TCH;t++){
        float dtv = dtp[t*DI_];
        float uv  = up[t*DI_];
        float du = dtv*uv;
        float yv = 0.f;
        #pragma unroll
        for (int s=0;s<NST;s++){
            float dA = __expf(dtv*A[s]);
            h[s] = dA*h[s] + du*Bl[t*NST+s];
            yv += h[s]*Cl[t*NST+s];
        }
        float zv = zp[t*DI_];
        vl[t*129+d] = (yv + uv*Dd)*silu_f(zv);
    }
    __syncthreads();
    // out-proj: 64 px x 64 o, K=128; thread: 4 px x 8 o
    int og=(tid&7)*8;       // 0..56
    int pg=(tid>>3)*4;      // 0..60
    float acc[4][8]={};
    for (int d0=0; d0<128; d0++){
        float bv[8];
        #pragma unroll
        for (int j=0;j<8;j++) bv[j]=Wl[d0*65+og+j];
        #pragma unroll
        for (int i=0;i<4;i++){
            float av=vl[(pg+i)*129+d0];
            #pragma unroll
            for (int j=0;j<8;j++) acc[i][j]+=av*bv[j];
        }
    }
    size_t prow=(size_t)b*L_ + l0;
    #pragma unroll
    for (int i=0;i<4;i++){
        size_t gi=(prow+pg+i)*64 + og;
        float4 r0=*(const float4*)(x0+gi);
        float4 r1=*(const float4*)(x0+gi+4);
        float4 o0={acc[i][0]+r0.x, acc[i][1]+r0.y, acc[i][2]+r0.z, acc[i][3]+r0.w};
        float4 o1={acc[i][4]+r1.x, acc[i][5]+r1.y, acc[i][6]+r1.z, acc[i][7]+r1.w};
        *(float4*)(x1+gi)   = o0;
        *(float4*)(x1+gi+4) = o1;
    }
}

extern "C" void kernel_launch(void* const* d_in, const int* in_sizes, int n_in,
                              void* d_out, int out_size, void* d_ws, size_t ws_size,
                              hipStream_t stream){
    const float* x      = (const float*)d_in[0];
    const float* ln_g   = (const float*)d_in[1];
    const float* ln_b   = (const float*)d_in[2];
    const float* w_pw1  = (const float*)d_in[3];
    const float* w_dw   = (const float*)d_in[4];
    const float* w_pw2  = (const float*)d_in[5];
    const float* w_odw1 = (const float*)d_in[6];
    const float* w_odw2 = (const float*)d_in[7];
    const float* W_inpj = (const float*)d_in[8];
    const float* conv_w = (const float*)d_in[9];
    const float* conv_b = (const float*)d_in[10];
    const float* W_xprj = (const float*)d_in[11];
    const float* W_dt   = (const float*)d_in[12];
    const float* b_dt   = (const float*)d_in[13];
    const float* A_log  = (const float*)d_in[14];
    const float* Dvec   = (const float*)d_in[15];
    const float* W_out  = (const float*)d_in[16];
    float* out = (float*)d_out;

    char* ws = (char*)d_ws;
    const size_t SZ64  = (size_t)NPIX*64*4;    // 16 MiB
    const size_t SZ128 = (size_t)NPIX*128*4;   // 32 MiB
    float* A1 = (float*)(ws);                  // x1
    float* A2 = (float*)(ws + SZ64);           // t1 -> {E,sumdt} -> t3
    float* A3 = (float*)(ws + 2*SZ64);         // t2 -> {Bm,Cm,Hst}
    float* A4 = (float*)(ws + 3*SZ64);         // x0
    float* A5 = (float*)(ws + 4*SZ64);         // xs
    float* A6 = (float*)(ws + 4*SZ64 + SZ128); // z
    float* A7 = (float*)(ws + 4*SZ64 + 2*SZ128); // u
    float* A8 = (float*)(ws + 4*SZ64 + 3*SZ128); // dt
    float* Ebuf  = A2;
    float* sumdt = (float*)((char*)A2 + (size_t)B_*NC*DI_*NST*4);
    float* Bmb = A3;
    float* Cmb = (float*)((char*)A3 + (size_t)NPIX*NST*4);
    float* Hst = (float*)((char*)A3 + (size_t)2*NPIX*NST*4);

    k_lnpw          <<<NPIX/64, 256, 0, stream>>>(x, ln_g, ln_b, w_pw1, A2);
    k_dw3<true,false><<<NPIX*64/256,256, 0, stream>>>(A2, w_dw, nullptr, A3);
    k_pw            <<<NPIX/64, 256, 0, stream>>>(A3, w_pw2, A4);
    k_inproj        <<<dim3(NPIX/64,2), 256, 0, stream>>>(A4, W_inpj, A5, A6);
    k_conv          <<<NPIX*128/256,256, 0, stream>>>(A5, conv_w, conv_b, A7);
    k_xproj         <<<NPIX/8,  128, 0, stream>>>(A7, W_xprj, W_dt, b_dt, A8, Bmb, Cmb);
    k_scanA         <<<B_*NC,   128, 0, stream>>>(A8, A7, Bmb, A_log, Ebuf, sumdt);
    k_scanB         <<<32,      256, 0, stream>>>(Ebuf, sumdt, A_log, Hst);
    k_scanC_gate    <<<B_*NC,   128, 0, stream>>>(A8, A7, Bmb, Cmb, A_log, Hst,
                                                  A6, Dvec, W_out, A4, A1);
    k_dw3<true,false><<<NPIX*64/256,256, 0, stream>>>(A1, w_odw1, nullptr, A2);
    k_dw3<false,true><<<NPIX*64/256,256, 0, stream>>>(A2, w_odw2, A1, out);
}

// Round 4
// 439.559 us; speedup vs baseline: 1.6896x; 1.2041x over previous
//
#include <hip/hip_runtime.h>
#include <hip/hip_bf16.h>
#include <math.h>

#define B_   4
#define H_   128
#define W_   128
#define C_   64
#define L_   (H_*W_)        // 16384 per batch
#define NPIX (B_*L_)        // 65536
#define DI_  128
#define NST  16
#define RT   4
#define TCH  64             // scan chunk length
#define NC   (L_/TCH)       // 256 chunks per batch

__device__ __forceinline__ float gelu_f(float x){
    return 0.5f*x*(1.f+erff(x*0.70710678118654752f));
}
__device__ __forceinline__ float silu_f(float x){
    return x/(1.f+__expf(-x));
}
__device__ __forceinline__ float softplus_f(float x){
    return (x>20.f)? x : log1pf(__expf(x));
}

// ---------------- fused LayerNorm + pw1: out[p,o] = sum_c LN(x)[p,c]*W[o,c]
// 256 thr, 64 px/block. Register-tiled 4x4.
__global__ void k_lnpw(const float* __restrict__ x, const float* __restrict__ g,
                       const float* __restrict__ b, const float* __restrict__ W,
                       float* __restrict__ out){
    __shared__ float xl[64*65];
    __shared__ float Wt[64*65];    // Wt[c*65+o] = W[o*64+c]
    int tid = threadIdx.x;
    for (int i=tid;i<4096;i+=256){ int o=i>>6, c=i&63; Wt[c*65+o]=W[i]; }
    size_t base = (size_t)blockIdx.x*64*64;
    int c  = tid&63;
    int pr = tid>>6;
    float gc=g[c], bc=b[c];
    for (int p=pr;p<64;p+=4){
        float v = x[base + p*64 + c];
        float s=v, s2=v*v;
        #pragma unroll
        for (int off=32; off; off>>=1){
            s  += __shfl_xor(s,  off, 64);
            s2 += __shfl_xor(s2, off, 64);
        }
        float mu = s*(1.f/64.f);
        float var= s2*(1.f/64.f) - mu*mu;
        float r  = rsqrtf(var + 1e-5f);
        xl[p*65+c] = (v-mu)*r*gc + bc;
    }
    __syncthreads();
    int og=(tid&15)*4, pg=(tid>>4)*4;
    float acc[4][4]={};
    for (int cc=0;cc<64;cc++){
        float bv[4], av[4];
        #pragma unroll
        for (int j=0;j<4;j++) bv[j]=Wt[cc*65+og+j];
        #pragma unroll
        for (int i=0;i<4;i++) av[i]=xl[(pg+i)*65+cc];
        #pragma unroll
        for (int i=0;i<4;i++)
            #pragma unroll
            for (int j=0;j<4;j++) acc[i][j]+=av[i]*bv[j];
    }
    #pragma unroll
    for (int i=0;i<4;i++){
        float4 v4 = {acc[i][0],acc[i][1],acc[i][2],acc[i][3]};
        *(float4*)(out + base + (pg+i)*64 + og) = v4;
    }
}

// ---------------- pointwise 64x64 (register-tiled 4x4)
__global__ void k_pw(const float* __restrict__ in, const float* __restrict__ W,
                     float* __restrict__ out){
    __shared__ float xl[64*65];
    __shared__ float Wt[64*65];
    int tid = threadIdx.x;
    for (int i=tid;i<4096;i+=256){ int o=i>>6, c=i&63; Wt[c*65+o]=W[i]; }
    size_t base = (size_t)blockIdx.x*64*64;
    for (int i=tid;i<4096;i+=256) xl[(i>>6)*65+(i&63)]=in[base+i];
    __syncthreads();
    int og=(tid&15)*4, pg=(tid>>4)*4;
    float acc[4][4]={};
    for (int cc=0;cc<64;cc++){
        float bv[4], av[4];
        #pragma unroll
        for (int j=0;j<4;j++) bv[j]=Wt[cc*65+og+j];
        #pragma unroll
        for (int i=0;i<4;i++) av[i]=xl[(pg+i)*65+cc];
        #pragma unroll
        for (int i=0;i<4;i++)
            #pragma unroll
            for (int j=0;j<4;j++) acc[i][j]+=av[i]*bv[j];
    }
    #pragma unroll
    for (int i=0;i<4;i++){
        float4 v4 = {acc[i][0],acc[i][1],acc[i][2],acc[i][3]};
        *(float4*)(out + base + (pg+i)*64 + og) = v4;
    }
}

// ---------------- depthwise 3x3 SAME (NHWC), optional exact-GELU, optional residual add
template<bool GELU, bool ADDRES>
__global__ void k_dw3(const float* __restrict__ in, const float* __restrict__ w9,
                      const float* __restrict__ res, float* __restrict__ out){
    int idx = blockIdx.x*256 + threadIdx.x;   // over NPIX*64
    int c = idx & 63;
    int p = idx >> 6;
    int j = p & (W_-1);
    int t = p >> 7;       // b*H + i   (W_=128)
    int i = t & (H_-1);
    int b = t >> 7;       // H_=128
    float acc = 0.f;
    #pragma unroll
    for (int ki=0;ki<3;ki++){
        int ii = i + ki - 1;
        if (ii<0||ii>=H_) continue;
        #pragma unroll
        for (int kj=0;kj<3;kj++){
            int jj = j + kj - 1;
            if (jj<0||jj>=W_) continue;
            acc += in[(((b*H_+ii)*W_+jj)<<6)+c]*w9[c*9+ki*3+kj];
        }
    }
    if (GELU)   acc = gelu_f(acc);
    if (ADDRES) acc += res[idx];
    out[idx] = acc;
}

// ---------------- in-projection: 64 px/block, o-half per blockIdx.y, 8x4 tiles
__global__ void k_inproj(const float* __restrict__ x0, const float* __restrict__ W,
                         float* __restrict__ xs, float* __restrict__ z){
    __shared__ float xl[64*65];
    __shared__ float Wt[64*129];   // Wt[c*129+o'] = Wh[o'*64+c], o' in half
    int tid=threadIdx.x;
    const float* Wh = W + (size_t)blockIdx.y*128*64;
    for (int i=tid;i<8192;i+=256){ int o=i>>6, c=i&63; Wt[c*129+o]=Wh[i]; }
    size_t base=(size_t)blockIdx.x*64*64;
    for (int i=tid;i<4096;i+=256) xl[(i>>6)*65+(i&63)]=x0[base+i];
    __syncthreads();
    int og=(tid>>3)*4;    // 0..124
    int pg=(tid&7)*8;     // 0..56
    float acc[8][4]={};
    for (int cc=0;cc<64;cc++){
        float bv[4];
        #pragma unroll
        for (int j=0;j<4;j++) bv[j]=Wt[cc*129+og+j];
        #pragma unroll
        for (int i=0;i<8;i++){
            float av=xl[(pg+i)*65+cc];
            #pragma unroll
            for (int j=0;j<4;j++) acc[i][j]+=av*bv[j];
        }
    }
    size_t prow=(size_t)blockIdx.x*64;
    float* dst = blockIdx.y ? z : xs;
    #pragma unroll
    for (int i=0;i<8;i++){
        float4 v4={acc[i][0],acc[i][1],acc[i][2],acc[i][3]};
        *(float4*)(dst + (prow+pg+i)*DI_ + og) = v4;
    }
}

// ---------------- causal depthwise conv1d (k=4) along L + SiLU
__global__ void k_conv(const float* __restrict__ xs, const float* __restrict__ cw,
                       const float* __restrict__ cb, float* __restrict__ u){
    int idx = blockIdx.x*256+threadIdx.x;   // NPIX*128
    int c = idx & 127;
    int t = idx >> 7;      // b*L + l
    int l = t & (L_-1);
    float acc = cb[c];
    #pragma unroll
    for (int k=0;k<4;k++){
        int ll = l + k - 3;
        if (ll>=0) acc += xs[idx + (k-3)*DI_]*cw[c*4+k];
    }
    u[idx]=silu_f(acc);
}

// ---------------- xproj: 64 px/block, 256 thr; x_dbl = u @ Wx^T, dt = softplus(dtr @ Wdt^T + bdt)
__global__ void k_xproj(const float* __restrict__ u, const float* __restrict__ Wx,
                        const float* __restrict__ Wdt, const float* __restrict__ bdt,
                        float* __restrict__ dt, float* __restrict__ Bm, float* __restrict__ Cm){
    __shared__ float ul[64*132];    // [p][d] pad132 (f4-aligned)
    __shared__ float Wxl[36*132];   // [j][d]
    __shared__ float sOut[64*37];   // [p][j] pad37 (5 mod 32 -> conflict-free)
    int tid=threadIdx.x;   // 256
    size_t pbase=(size_t)blockIdx.x*64;
    for (int i=tid;i<1152;i+=256){ int j=i>>5, dq=i&31;
        ((float4*)(Wxl+j*132))[dq] = ((const float4*)(Wx+j*128))[dq]; }
    for (int i=tid;i<2048;i+=256){ int p=i>>5, dq=i&31;
        ((float4*)(ul+p*132))[dq] = ((const float4*)(u+(pbase+p)*DI_))[dq]; }
    __syncthreads();
    int px = tid & 63;
    int og = tid >> 6;     // 0..3
    float acc[9]={};
    const float4* a4=(const float4*)(ul+px*132);
    for (int d4=0; d4<32; d4++){
        float4 a=a4[d4];
        #pragma unroll
        for (int k=0;k<9;k++){
            const float4 w = ((const float4*)(Wxl+(og+k*4)*132))[d4];
            acc[k] += a.x*w.x + a.y*w.y + a.z*w.z + a.w*w.w;
        }
    }
    #pragma unroll
    for (int k=0;k<9;k++) sOut[px*37 + og + k*4] = acc[k];
    __syncthreads();
    for (int i=tid;i<1024;i+=256){
        int p=i>>4, s=i&15;
        Bm[(pbase+p)*NST+s] = sOut[p*37+RT+s];
        Cm[(pbase+p)*NST+s] = sOut[p*37+RT+NST+s];
    }
    int d=tid&127;
    float w0=Wdt[d*4+0], w1=Wdt[d*4+1], w2=Wdt[d*4+2], w3=Wdt[d*4+3];
    float bd=bdt[d];
    for (int p=(tid>>7); p<64; p+=2){
        float a2 = bd + sOut[p*37+0]*w0 + sOut[p*37+1]*w1 + sOut[p*37+2]*w2 + sOut[p*37+3]*w3;
        dt[(pbase+p)*DI_+d]=softplus_f(a2);
    }
}

// ---------------- scan pass A: 512 thr, thread=(sg,d); 4 states per thread
__global__ void k_scanA(const float* __restrict__ dt, const float* __restrict__ u,
                        const float* __restrict__ Bm, const float* __restrict__ Alog,
                        float* __restrict__ E, float* __restrict__ sumdt){
    __shared__ float Bl[TCH*NST];
    int tid=threadIdx.x;       // 512
    int blk=blockIdx.x;        // b*NC + k
    int b = blk >> 8;
    int k = blk & 255;
    int l0 = k*TCH;
    for (int i=tid;i<TCH*NST;i+=512) Bl[i]=Bm[((size_t)b*L_+l0)*NST+i];
    __syncthreads();
    int sg = tid >> 7;         // 0..3 (state group)
    int d  = tid & 127;
    float4 al = *(const float4*)(Alog + d*NST + sg*4);
    float A0=-__expf(al.x), A1=-__expf(al.y), A2=-__expf(al.z), A3=-__expf(al.w);
    float h0=0.f,h1=0.f,h2=0.f,h3=0.f;
    float sd=0.f;
    const float* dtp = dt + ((size_t)b*L_+l0)*DI_ + d;
    const float* up  = u  + ((size_t)b*L_+l0)*DI_ + d;
    for (int t=0;t<TCH;t++){
        float dtv = dtp[t*DI_];
        float uv  = up[t*DI_];
        sd += dtv;
        float du = dtv*uv;
        const float* Bp = Bl + t*NST + sg*4;
        h0 = __expf(dtv*A0)*h0 + du*Bp[0];
        h1 = __expf(dtv*A1)*h1 + du*Bp[1];
        h2 = __expf(dtv*A2)*h2 + du*Bp[2];
        h3 = __expf(dtv*A3)*h3 + du*Bp[3];
    }
    float4 hv = {h0,h1,h2,h3};
    *(float4*)(E + ((size_t)blk*DI_+d)*NST + sg*4) = hv;
    if (sg==0) sumdt[(size_t)blk*DI_+d]=sd;
}

// ---------------- scan pass B: chunk-level recurrence -> start state per chunk
__global__ void k_scanB(const float* __restrict__ E, const float* __restrict__ sumdt,
                        const float* __restrict__ Alog, float* __restrict__ Hst){
    int idx = blockIdx.x*256+threadIdx.x;  // B*DI*NST = 8192
    if (idx >= B_*DI_*NST) return;
    int s = idx & 15;
    int d = (idx>>4) & 127;
    int b = idx >> 11;
    float Av = -__expf(Alog[d*NST+s]);
    float h = 0.f;
    #pragma unroll 4
    for (int k=0;k<NC;k++){
        size_t base = ((size_t)(b*NC+k)*DI_+d);
        Hst[base*NST+s] = h;
        float P = __expf(Av * sumdt[base]);
        h = P*h + E[base*NST+s];
    }
}

// ---------------- scan pass C: 512 thr, thread=(d,sg); y via shfl; writes gated v
__global__ void k_scanC(const float* __restrict__ dt, const float* __restrict__ u,
                        const float* __restrict__ Bm, const float* __restrict__ Cm,
                        const float* __restrict__ Alog, const float* __restrict__ Hst,
                        const float* __restrict__ z, const float* __restrict__ Dv,
                        float* __restrict__ v){
    __shared__ float Bl[TCH*NST];
    __shared__ float Cl[TCH*NST];
    int tid=threadIdx.x;   // 512
    int blk=blockIdx.x;
    int b = blk >> 8;
    int k = blk & 255;
    int l0 = k*TCH;
    for (int i=tid;i<TCH*NST;i+=512){
        Bl[i]=Bm[((size_t)b*L_+l0)*NST+i];
        Cl[i]=Cm[((size_t)b*L_+l0)*NST+i];
    }
    __syncthreads();
    int d  = tid >> 2;     // 0..127
    int sg = tid & 3;      // state group
    float4 al = *(const float4*)(Alog + d*NST + sg*4);
    float A0=-__expf(al.x), A1=-__expf(al.y), A2=-__expf(al.z), A3=-__expf(al.w);
    float4 hv = *(const float4*)(Hst + ((size_t)blk*DI_+d)*NST + sg*4);
    float h0=hv.x,h1=hv.y,h2=hv.z,h3=hv.w;
    const float* dtp = dt + ((size_t)b*L_+l0)*DI_ + d;
    const float* up  = u  + ((size_t)b*L_+l0)*DI_ + d;
    const float* zp  = z  + ((size_t)b*L_+l0)*DI_ + d;
    float* vp = v + ((size_t)b*L_+l0)*DI_ + d;
    float Dd = Dv[d];
    for (int t=0;t<TCH;t++){
        float dtv = dtp[t*DI_];
        float uv  = up[t*DI_];
        float du = dtv*uv;
        const float* Bp = Bl + t*NST + sg*4;
        const float* Cp = Cl + t*NST + sg*4;
        float yv;
        h0 = __expf(dtv*A0)*h0 + du*Bp[0];
        yv  = h0*Cp[0];
        h1 = __expf(dtv*A1)*h1 + du*Bp[1];
        yv += h1*Cp[1];
        h2 = __expf(dtv*A2)*h2 + du*Bp[2];
        yv += h2*Cp[2];
        h3 = __expf(dtv*A3)*h3 + du*Bp[3];
        yv += h3*Cp[3];
        yv += __shfl_xor(yv, 1, 64);
        yv += __shfl_xor(yv, 2, 64);
        if (sg==0){
            float zv = zp[t*DI_];
            vp[t*DI_] = (yv + uv*Dd)*silu_f(zv);
        }
    }
}

// ---------------- gate GEMM: x1 = v @ Wout^T + x0 ; 64 px/block, 256 thr, 4x4 tiles, f4 K-loop
__global__ void k_gate_out(const float* __restrict__ v, const float* __restrict__ Wout,
                           const float* __restrict__ x0, float* __restrict__ x1){
    __shared__ float vl[64*132];   // [p][d]
    __shared__ float Wl[64*132];   // [o][d]  (row-major copy, no transpose)
    int tid=threadIdx.x;   // 256
    size_t pbase=(size_t)blockIdx.x*64;
    for (int i=tid;i<2048;i+=256){ int o=i>>5, dq=i&31;
        ((float4*)(Wl+o*132))[dq] = ((const float4*)(Wout+o*DI_))[dq]; }
    for (int i=tid;i<2048;i+=256){ int p=i>>5, dq=i&31;
        ((float4*)(vl+p*132))[dq] = ((const float4*)(v+(pbase+p)*DI_))[dq]; }
    __syncthreads();
    int og=(tid&15)*4, pg=(tid>>4)*4;
    float acc[4][4]={};
    for (int d4=0; d4<32; d4++){
        float4 wv[4], av[4];
        #pragma unroll
        for (int j=0;j<4;j++) wv[j]=((const float4*)(Wl+(og+j)*132))[d4];
        #pragma unroll
        for (int i=0;i<4;i++) av[i]=((const float4*)(vl+(pg+i)*132))[d4];
        #pragma unroll
        for (int i=0;i<4;i++)
            #pragma unroll
            for (int j=0;j<4;j++)
                acc[i][j] += av[i].x*wv[j].x + av[i].y*wv[j].y
                           + av[i].z*wv[j].z + av[i].w*wv[j].w;
    }
    #pragma unroll
    for (int i=0;i<4;i++){
        size_t gi=(pbase+pg+i)*64+og;
        float4 r=*(const float4*)(x0+gi);
        float4 o4={acc[i][0]+r.x, acc[i][1]+r.y, acc[i][2]+r.z, acc[i][3]+r.w};
        *(float4*)(x1+gi)=o4;
    }
}

extern "C" void kernel_launch(void* const* d_in, const int* in_sizes, int n_in,
                              void* d_out, int out_size, void* d_ws, size_t ws_size,
                              hipStream_t stream){
    const float* x      = (const float*)d_in[0];
    const float* ln_g   = (const float*)d_in[1];
    const float* ln_b   = (const float*)d_in[2];
    const float* w_pw1  = (const float*)d_in[3];
    const float* w_dw   = (const float*)d_in[4];
    const float* w_pw2  = (const float*)d_in[5];
    const float* w_odw1 = (const float*)d_in[6];
    const float* w_odw2 = (const float*)d_in[7];
    const float* W_inpj = (const float*)d_in[8];
    const float* conv_w = (const float*)d_in[9];
    const float* conv_b = (const float*)d_in[10];
    const float* W_xprj = (const float*)d_in[11];
    const float* W_dt   = (const float*)d_in[12];
    const float* b_dt   = (const float*)d_in[13];
    const float* A_log  = (const float*)d_in[14];
    const float* Dvec   = (const float*)d_in[15];
    const float* W_out  = (const float*)d_in[16];
    float* out = (float*)d_out;

    char* ws = (char*)d_ws;
    const size_t SZ64  = (size_t)NPIX*64*4;    // 16 MiB
    const size_t SZ128 = (size_t)NPIX*128*4;   // 32 MiB
    float* A1 = (float*)(ws);                  // x1
    float* A2 = (float*)(ws + SZ64);           // t1 -> {E,sumdt} -> t3
    float* A3 = (float*)(ws + 2*SZ64);         // t2 -> {Bm,Cm,Hst}
    float* A4 = (float*)(ws + 3*SZ64);         // x0
    float* A5 = (float*)(ws + 4*SZ64);         // xs -> v
    float* A6 = (float*)(ws + 4*SZ64 + SZ128); // z
    float* A7 = (float*)(ws + 4*SZ64 + 2*SZ128); // u
    float* A8 = (float*)(ws + 4*SZ64 + 3*SZ128); // dt
    float* Ebuf  = A2;
    float* sumdt = (float*)((char*)A2 + (size_t)B_*NC*DI_*NST*4);
    float* Bmb = A3;
    float* Cmb = (float*)((char*)A3 + (size_t)NPIX*NST*4);
    float* Hst = (float*)((char*)A3 + (size_t)2*NPIX*NST*4);

    k_lnpw          <<<NPIX/64, 256, 0, stream>>>(x, ln_g, ln_b, w_pw1, A2);
    k_dw3<true,false><<<NPIX*64/256,256, 0, stream>>>(A2, w_dw, nullptr, A3);
    k_pw            <<<NPIX/64, 256, 0, stream>>>(A3, w_pw2, A4);
    k_inproj        <<<dim3(NPIX/64,2), 256, 0, stream>>>(A4, W_inpj, A5, A6);
    k_conv          <<<NPIX*128/256,256, 0, stream>>>(A5, conv_w, conv_b, A7);
    k_xproj         <<<NPIX/64, 256, 0, stream>>>(A7, W_xprj, W_dt, b_dt, A8, Bmb, Cmb);
    k_scanA         <<<B_*NC,   512, 0, stream>>>(A8, A7, Bmb, A_log, Ebuf, sumdt);
    k_scanB         <<<32,      256, 0, stream>>>(Ebuf, sumdt, A_log, Hst);
    k_scanC         <<<B_*NC,   512, 0, stream>>>(A8, A7, Bmb, Cmb, A_log, Hst,
                                                  A6, Dvec, A5);
    k_gate_out      <<<NPIX/64, 256, 0, stream>>>(A5, W_out, A4, A1);
    k_dw3<true,false><<<NPIX*64/256,256, 0, stream>>>(A1, w_odw1, nullptr, A2);
    k_dw3<false,true><<<NPIX*64/256,256, 0, stream>>>(A2, w_odw2, A1, out);
}

// Round 5
// 422.620 us; speedup vs baseline: 1.7573x; 1.0401x over previous
//
#include <hip/hip_runtime.h>
#include <hip/hip_bf16.h>
#include <math.h>

#define B_   4
#define H_   128
#define W_   128
#define C_   64
#define L_   (H_*W_)        // 16384 per batch
#define NPIX (B_*L_)        // 65536
#define DI_  128
#define NST  16
#define RT   4
#define TCH  64             // scan chunk length
#define NC   (L_/TCH)       // 256 chunks per batch

__device__ __forceinline__ float gelu_f(float x){
    return 0.5f*x*(1.f+erff(x*0.70710678118654752f));
}
__device__ __forceinline__ float silu_f(float x){
    return x/(1.f+__expf(-x));
}
__device__ __forceinline__ float softplus_f(float x){
    return (x>20.f)? x : log1pf(__expf(x));
}

// ---------------- fused LayerNorm + pw1 (register-tiled 4x4)
__global__ void k_lnpw(const float* __restrict__ x, const float* __restrict__ g,
                       const float* __restrict__ b, const float* __restrict__ W,
                       float* __restrict__ out){
    __shared__ float xl[64*65];
    __shared__ float Wt[64*65];    // Wt[c*65+o] = W[o*64+c]
    int tid = threadIdx.x;
    for (int i=tid;i<4096;i+=256){ int o=i>>6, c=i&63; Wt[c*65+o]=W[i]; }
    size_t base = (size_t)blockIdx.x*64*64;
    int c  = tid&63;
    int pr = tid>>6;
    float gc=g[c], bc=b[c];
    for (int p=pr;p<64;p+=4){
        float v = x[base + p*64 + c];
        float s=v, s2=v*v;
        #pragma unroll
        for (int off=32; off; off>>=1){
            s  += __shfl_xor(s,  off, 64);
            s2 += __shfl_xor(s2, off, 64);
        }
        float mu = s*(1.f/64.f);
        float var= s2*(1.f/64.f) - mu*mu;
        float r  = rsqrtf(var + 1e-5f);
        xl[p*65+c] = (v-mu)*r*gc + bc;
    }
    __syncthreads();
    int og=(tid&15)*4, pg=(tid>>4)*4;
    float acc[4][4]={};
    for (int cc=0;cc<64;cc++){
        float bv[4], av[4];
        #pragma unroll
        for (int j=0;j<4;j++) bv[j]=Wt[cc*65+og+j];
        #pragma unroll
        for (int i=0;i<4;i++) av[i]=xl[(pg+i)*65+cc];
        #pragma unroll
        for (int i=0;i<4;i++)
            #pragma unroll
            for (int j=0;j<4;j++) acc[i][j]+=av[i]*bv[j];
    }
    #pragma unroll
    for (int i=0;i<4;i++){
        float4 v4 = {acc[i][0],acc[i][1],acc[i][2],acc[i][3]};
        *(float4*)(out + base + (pg+i)*64 + og) = v4;
    }
}

// ---------------- pointwise 64x64 (register-tiled 4x4)
__global__ void k_pw(const float* __restrict__ in, const float* __restrict__ W,
                     float* __restrict__ out){
    __shared__ float xl[64*65];
    __shared__ float Wt[64*65];
    int tid = threadIdx.x;
    for (int i=tid;i<4096;i+=256){ int o=i>>6, c=i&63; Wt[c*65+o]=W[i]; }
    size_t base = (size_t)blockIdx.x*64*64;
    for (int i=tid;i<4096;i+=256) xl[(i>>6)*65+(i&63)]=in[base+i];
    __syncthreads();
    int og=(tid&15)*4, pg=(tid>>4)*4;
    float acc[4][4]={};
    for (int cc=0;cc<64;cc++){
        float bv[4], av[4];
        #pragma unroll
        for (int j=0;j<4;j++) bv[j]=Wt[cc*65+og+j];
        #pragma unroll
        for (int i=0;i<4;i++) av[i]=xl[(pg+i)*65+cc];
        #pragma unroll
        for (int i=0;i<4;i++)
            #pragma unroll
            for (int j=0;j<4;j++) acc[i][j]+=av[i]*bv[j];
    }
    #pragma unroll
    for (int i=0;i<4;i++){
        float4 v4 = {acc[i][0],acc[i][1],acc[i][2],acc[i][3]};
        *(float4*)(out + base + (pg+i)*64 + og) = v4;
    }
}

// ---------------- depthwise 3x3 SAME (NHWC), optional exact-GELU, optional residual add
template<bool GELU, bool ADDRES>
__global__ void k_dw3(const float* __restrict__ in, const float* __restrict__ w9,
                      const float* __restrict__ res, float* __restrict__ out){
    int idx = blockIdx.x*256 + threadIdx.x;   // over NPIX*64
    int c = idx & 63;
    int p = idx >> 6;
    int j = p & (W_-1);
    int t = p >> 7;       // b*H + i   (W_=128)
    int i = t & (H_-1);
    int b = t >> 7;       // H_=128
    float acc = 0.f;
    #pragma unroll
    for (int ki=0;ki<3;ki++){
        int ii = i + ki - 1;
        if (ii<0||ii>=H_) continue;
        #pragma unroll
        for (int kj=0;kj<3;kj++){
            int jj = j + kj - 1;
            if (jj<0||jj>=W_) continue;
            acc += in[(((b*H_+ii)*W_+jj)<<6)+c]*w9[c*9+ki*3+kj];
        }
    }
    if (GELU)   acc = gelu_f(acc);
    if (ADDRES) acc += res[idx];
    out[idx] = acc;
}

// ---------------- in-projection: 64 px/block, o-half per blockIdx.y, 8x4 tiles
__global__ void k_inproj(const float* __restrict__ x0, const float* __restrict__ W,
                         float* __restrict__ xs, float* __restrict__ z){
    __shared__ float xl[64*65];
    __shared__ float Wt[64*129];   // Wt[c*129+o'] = Wh[o'*64+c], o' in half
    int tid=threadIdx.x;
    const float* Wh = W + (size_t)blockIdx.y*128*64;
    for (int i=tid;i<8192;i+=256){ int o=i>>6, c=i&63; Wt[c*129+o]=Wh[i]; }
    size_t base=(size_t)blockIdx.x*64*64;
    for (int i=tid;i<4096;i+=256) xl[(i>>6)*65+(i&63)]=x0[base+i];
    __syncthreads();
    int og=(tid>>3)*4;    // 0..124
    int pg=(tid&7)*8;     // 0..56
    float acc[8][4]={};
    for (int cc=0;cc<64;cc++){
        float bv[4];
        #pragma unroll
        for (int j=0;j<4;j++) bv[j]=Wt[cc*129+og+j];
        #pragma unroll
        for (int i=0;i<8;i++){
            float av=xl[(pg+i)*65+cc];
            #pragma unroll
            for (int j=0;j<4;j++) acc[i][j]+=av*bv[j];
        }
    }
    size_t prow=(size_t)blockIdx.x*64;
    float* dst = blockIdx.y ? z : xs;
    #pragma unroll
    for (int i=0;i<8;i++){
        float4 v4={acc[i][0],acc[i][1],acc[i][2],acc[i][3]};
        *(float4*)(dst + (prow+pg+i)*DI_ + og) = v4;
    }
}

// ---------------- fused causal conv1d(k=4)+SiLU + xproj + dt
// 256 thr, 64 px (one scan-chunk) per block.
__global__ void k_convxproj(const float* __restrict__ xs, const float* __restrict__ cw,
                            const float* __restrict__ cb, const float* __restrict__ Wx,
                            const float* __restrict__ Wdt, const float* __restrict__ bdt,
                            float* __restrict__ u, float* __restrict__ dt,
                            float* __restrict__ Bm, float* __restrict__ Cm){
    __shared__ float ul[64*128];    // [px][d], f4-col swizzled: col' = col ^ (px&7)
    __shared__ float sOut[64*37];   // [px][j]
    int tid=threadIdx.x;   // 256
    int blk=blockIdx.x;    // b*NC + chunk
    int b  = blk >> 8;
    int l0 = (blk & 255)*64;
    // phase 1: conv + silu -> ul (swizzled) + u (global)
    for (int i=tid;i<8192;i+=256){
        int d  = i & 127;
        int px = i >> 7;
        int l  = l0 + px;
        float acc = cb[d];
        #pragma unroll
        for (int k=0;k<4;k++){
            int ll = l + k - 3;
            if (ll>=0) acc += xs[((size_t)b*L_+ll)*DI_ + d]*cw[d*4+k];
        }
        float uvv = silu_f(acc);
        int col = (d>>2) ^ (px&7);
        ul[px*128 + col*4 + (d&3)] = uvv;
        u[((size_t)b*L_+l)*DI_ + d] = uvv;
    }
    __syncthreads();
    // phase 2: GEMM 64px x 36out, K=128. A: 1 ds_read_b128/iter; W: scalar loads.
    {
        int px = tid & 63;
        int og = __builtin_amdgcn_readfirstlane(tid >> 6);   // 0..3, wave-uniform
        float acc[9]={};
        const float4* ul4 = (const float4*)ul;
        for (int d4=0; d4<32; d4++){
            float4 a = ul4[px*32 + (d4 ^ (px&7))];
            #pragma unroll
            for (int k=0;k<9;k++){
                const float4 w = *(const float4*)(Wx + (og+k*4)*128 + d4*4);
                acc[k] += a.x*w.x + a.y*w.y + a.z*w.z + a.w*w.w;
            }
        }
        #pragma unroll
        for (int k=0;k<9;k++) sOut[px*37 + og + k*4] = acc[k];
    }
    __syncthreads();
    size_t pbase=(size_t)blk*64;
    for (int i=tid;i<1024;i+=256){
        int p=i>>4, s=i&15;
        Bm[(pbase+p)*NST+s] = sOut[p*37+RT+s];
        Cm[(pbase+p)*NST+s] = sOut[p*37+RT+NST+s];
    }
    int d=tid&127;
    float w0=Wdt[d*4+0], w1=Wdt[d*4+1], w2=Wdt[d*4+2], w3=Wdt[d*4+3];
    float bd=bdt[d];
    for (int p=(tid>>7); p<64; p+=2){
        float a2 = bd + sOut[p*37+0]*w0 + sOut[p*37+1]*w1 + sOut[p*37+2]*w2 + sOut[p*37+3]*w3;
        dt[(pbase+p)*DI_+d]=softplus_f(a2);
    }
}

// ---------------- scan pass A: 512 thr, thread=(sg,d); 8-deep double-buffered prefetch
#define LGA(D,U,t0) _Pragma("unroll") for(int q=0;q<8;q++){ D[q]=dtp[((t0)+q)*DI_]; U[q]=up[((t0)+q)*DI_]; }
#define STA(D,U,t0) _Pragma("unroll") for(int q=0;q<8;q++){ \
    float dtv=D[q]; float du=dtv*U[q]; sd+=dtv; \
    const float4 Bv=*(const float4*)(Bl+((t0)+q)*NST+sg*4); \
    h0=__expf(dtv*A0)*h0+du*Bv.x; h1=__expf(dtv*A1)*h1+du*Bv.y; \
    h2=__expf(dtv*A2)*h2+du*Bv.z; h3=__expf(dtv*A3)*h3+du*Bv.w; }

__global__ void k_scanA(const float* __restrict__ dt, const float* __restrict__ u,
                        const float* __restrict__ Bm, const float* __restrict__ Alog,
                        float* __restrict__ E, float* __restrict__ sumdt){
    __shared__ float Bl[TCH*NST];
    int tid=threadIdx.x;       // 512
    int blk=blockIdx.x;
    int b = blk >> 8;
    int k = blk & 255;
    int l0 = k*TCH;
    for (int i=tid;i<TCH*NST;i+=512) Bl[i]=Bm[((size_t)b*L_+l0)*NST+i];
    __syncthreads();
    int sg = tid >> 7;         // 0..3
    int d  = tid & 127;
    float4 al = *(const float4*)(Alog + d*NST + sg*4);
    float A0=-__expf(al.x), A1=-__expf(al.y), A2=-__expf(al.z), A3=-__expf(al.w);
    float h0=0.f,h1=0.f,h2=0.f,h3=0.f,sd=0.f;
    const float* dtp = dt + ((size_t)b*L_+l0)*DI_ + d;
    const float* up  = u  + ((size_t)b*L_+l0)*DI_ + d;
    float dA[8],uA[8],dB[8],uB[8];
    LGA(dA,uA,0);
    for (int t0=0;t0<TCH;t0+=16){
        LGA(dB,uB,t0+8);
        STA(dA,uA,t0);
        if (t0+16<TCH){ LGA(dA,uA,t0+16); }
        STA(dB,uB,t0+8);
    }
    float4 hv = {h0,h1,h2,h3};
    *(float4*)(E + ((size_t)blk*DI_+d)*NST + sg*4) = hv;
    if (sg==0) sumdt[(size_t)blk*DI_+d]=sd;
}

// ---------------- scan pass B: chunk-level recurrence, 8-deep prefetch
#define LGB(EB,SB,kk) _Pragma("unroll") for(int q=0;q<8;q++){ \
    size_t base=((size_t)(b*NC+(kk)+q)*DI_+d); EB[q]=E[base*NST+s]; SB[q]=sumdt[base]; }
#define STB(EB,SB,kk) _Pragma("unroll") for(int q=0;q<8;q++){ \
    size_t base=((size_t)(b*NC+(kk)+q)*DI_+d); Hst[base*NST+s]=h; \
    h = __expf(Av*SB[q])*h + EB[q]; }

__global__ void k_scanB(const float* __restrict__ E, const float* __restrict__ sumdt,
                        const float* __restrict__ Alog, float* __restrict__ Hst){
    int idx = blockIdx.x*256+threadIdx.x;  // B*DI*NST = 8192
    if (idx >= B_*DI_*NST) return;
    int s = idx & 15;
    int d = (idx>>4) & 127;
    int b = idx >> 11;
    float Av = -__expf(Alog[d*NST+s]);
    float h = 0.f;
    float eA[8],sA[8],eB[8],sB[8];
    LGB(eA,sA,0);
    for (int k=0;k<NC;k+=16){
        LGB(eB,sB,k+8);
        STB(eA,sA,k);
        if (k+16<NC){ LGB(eA,sA,k+16); }
        STB(eB,sB,k+8);
    }
}

// ---------------- scan pass C: 512 thr, thread=(d,sg); prefetch; writes gated v
#define LGC(D,U,Z,t0) _Pragma("unroll") for(int q=0;q<8;q++){ \
    D[q]=dtp[((t0)+q)*DI_]; U[q]=up[((t0)+q)*DI_]; Z[q]=zp[((t0)+q)*DI_]; }
#define STC(D,U,Z,t0) _Pragma("unroll") for(int q=0;q<8;q++){ \
    float dtv=D[q]; float uv=U[q]; float du=dtv*uv; \
    const float4 Bv=*(const float4*)(Bl+((t0)+q)*NST+sg*4); \
    const float4 Cv=*(const float4*)(Cl+((t0)+q)*NST+sg*4); \
    float yv; \
    h0=__expf(dtv*A0)*h0+du*Bv.x; yv =h0*Cv.x; \
    h1=__expf(dtv*A1)*h1+du*Bv.y; yv+=h1*Cv.y; \
    h2=__expf(dtv*A2)*h2+du*Bv.z; yv+=h2*Cv.z; \
    h3=__expf(dtv*A3)*h3+du*Bv.w; yv+=h3*Cv.w; \
    yv += __shfl_xor(yv,1,64); yv += __shfl_xor(yv,2,64); \
    if (sg==0) vp[((t0)+q)*DI_] = (yv + uv*Dd)*silu_f(Z[q]); }

__global__ void k_scanC(const float* __restrict__ dt, const float* __restrict__ u,
                        const float* __restrict__ Bm, const float* __restrict__ Cm,
                        const float* __restrict__ Alog, const float* __restrict__ Hst,
                        const float* __restrict__ z, const float* __restrict__ Dv,
                        float* __restrict__ v){
    __shared__ float Bl[TCH*NST];
    __shared__ float Cl[TCH*NST];
    int tid=threadIdx.x;   // 512
    int blk=blockIdx.x;
    int b = blk >> 8;
    int k = blk & 255;
    int l0 = k*TCH;
    for (int i=tid;i<TCH*NST;i+=512){
        Bl[i]=Bm[((size_t)b*L_+l0)*NST+i];
        Cl[i]=Cm[((size_t)b*L_+l0)*NST+i];
    }
    __syncthreads();
    int d  = tid >> 2;     // 0..127
    int sg = tid & 3;
    float4 al = *(const float4*)(Alog + d*NST + sg*4);
    float A0=-__expf(al.x), A1=-__expf(al.y), A2=-__expf(al.z), A3=-__expf(al.w);
    float4 hv = *(const float4*)(Hst + ((size_t)blk*DI_+d)*NST + sg*4);
    float h0=hv.x,h1=hv.y,h2=hv.z,h3=hv.w;
    const float* dtp = dt + ((size_t)b*L_+l0)*DI_ + d;
    const float* up  = u  + ((size_t)b*L_+l0)*DI_ + d;
    const float* zp  = z  + ((size_t)b*L_+l0)*DI_ + d;
    float* vp = v + ((size_t)b*L_+l0)*DI_ + d;
    float Dd = Dv[d];
    float dA[8],uA[8],zA[8],dB[8],uB[8],zB[8];
    LGC(dA,uA,zA,0);
    for (int t0=0;t0<TCH;t0+=16){
        LGC(dB,uB,zB,t0+8);
        STC(dA,uA,zA,t0);
        if (t0+16<TCH){ LGC(dA,uA,zA,t0+16); }
        STC(dB,uB,zB,t0+8);
    }
}

// ---------------- gate GEMM: x1 = v @ Wout^T + x0 ; 64 px/block, 256 thr, 4x4 tiles
__global__ void k_gate_out(const float* __restrict__ v, const float* __restrict__ Wout,
                           const float* __restrict__ x0, float* __restrict__ x1){
    __shared__ float vl[64*132];   // [p][d]
    __shared__ float Wl[64*132];   // [o][d]
    int tid=threadIdx.x;   // 256
    size_t pbase=(size_t)blockIdx.x*64;
    for (int i=tid;i<2048;i+=256){ int o=i>>5, dq=i&31;
        ((float4*)(Wl+o*132))[dq] = ((const float4*)(Wout+o*DI_))[dq]; }
    for (int i=tid;i<2048;i+=256){ int p=i>>5, dq=i&31;
        ((float4*)(vl+p*132))[dq] = ((const float4*)(v+(pbase+p)*DI_))[dq]; }
    __syncthreads();
    int og=(tid&15)*4, pg=(tid>>4)*4;
    float acc[4][4]={};
    for (int d4=0; d4<32; d4++){
        float4 wv[4], av[4];
        #pragma unroll
        for (int j=0;j<4;j++) wv[j]=((const float4*)(Wl+(og+j)*132))[d4];
        #pragma unroll
        for (int i=0;i<4;i++) av[i]=((const float4*)(vl+(pg+i)*132))[d4];
        #pragma unroll
        for (int i=0;i<4;i++)
            #pragma unroll
            for (int j=0;j<4;j++)
                acc[i][j] += av[i].x*wv[j].x + av[i].y*wv[j].y
                           + av[i].z*wv[j].z + av[i].w*wv[j].w;
    }
    #pragma unroll
    for (int i=0;i<4;i++){
        size_t gi=(pbase+pg+i)*64+og;
        float4 r=*(const float4*)(x0+gi);
        float4 o4={acc[i][0]+r.x, acc[i][1]+r.y, acc[i][2]+r.z, acc[i][3]+r.w};
        *(float4*)(x1+gi)=o4;
    }
}

extern "C" void kernel_launch(void* const* d_in, const int* in_sizes, int n_in,
                              void* d_out, int out_size, void* d_ws, size_t ws_size,
                              hipStream_t stream){
    const float* x      = (const float*)d_in[0];
    const float* ln_g   = (const float*)d_in[1];
    const float* ln_b   = (const float*)d_in[2];
    const float* w_pw1  = (const float*)d_in[3];
    const float* w_dw   = (const float*)d_in[4];
    const float* w_pw2  = (const float*)d_in[5];
    const float* w_odw1 = (const float*)d_in[6];
    const float* w_odw2 = (const float*)d_in[7];
    const float* W_inpj = (const float*)d_in[8];
    const float* conv_w = (const float*)d_in[9];
    const float* conv_b = (const float*)d_in[10];
    const float* W_xprj = (const float*)d_in[11];
    const float* W_dt   = (const float*)d_in[12];
    const float* b_dt   = (const float*)d_in[13];
    const float* A_log  = (const float*)d_in[14];
    const float* Dvec   = (const float*)d_in[15];
    const float* W_out  = (const float*)d_in[16];
    float* out = (float*)d_out;

    char* ws = (char*)d_ws;
    const size_t SZ64  = (size_t)NPIX*64*4;    // 16 MiB
    const size_t SZ128 = (size_t)NPIX*128*4;   // 32 MiB
    float* A1 = (float*)(ws);                  // x1
    float* A2 = (float*)(ws + SZ64);           // t1 -> {E,sumdt} -> t3
    float* A3 = (float*)(ws + 2*SZ64);         // t2 -> {Bm,Cm,Hst}
    float* A4 = (float*)(ws + 3*SZ64);         // x0
    float* A5 = (float*)(ws + 4*SZ64);         // xs -> v
    float* A6 = (float*)(ws + 4*SZ64 + SZ128); // z
    float* A7 = (float*)(ws + 4*SZ64 + 2*SZ128); // u
    float* A8 = (float*)(ws + 4*SZ64 + 3*SZ128); // dt
    float* Ebuf  = A2;
    float* sumdt = (float*)((char*)A2 + (size_t)B_*NC*DI_*NST*4);
    float* Bmb = A3;
    float* Cmb = (float*)((char*)A3 + (size_t)NPIX*NST*4);
    float* Hst = (float*)((char*)A3 + (size_t)2*NPIX*NST*4);

    k_lnpw          <<<NPIX/64, 256, 0, stream>>>(x, ln_g, ln_b, w_pw1, A2);
    k_dw3<true,false><<<NPIX*64/256,256, 0, stream>>>(A2, w_dw, nullptr, A3);
    k_pw            <<<NPIX/64, 256, 0, stream>>>(A3, w_pw2, A4);
    k_inproj        <<<dim3(NPIX/64,2), 256, 0, stream>>>(A4, W_inpj, A5, A6);
    k_convxproj     <<<B_*NC,   256, 0, stream>>>(A5, conv_w, conv_b, W_xprj,
                                                  W_dt, b_dt, A7, A8, Bmb, Cmb);
    k_scanA         <<<B_*NC,   512, 0, stream>>>(A8, A7, Bmb, A_log, Ebuf, sumdt);
    k_scanB         <<<32,      256, 0, stream>>>(Ebuf, sumdt, A_log, Hst);
    k_scanC         <<<B_*NC,   512, 0, stream>>>(A8, A7, Bmb, Cmb, A_log, Hst,
                                                  A6, Dvec, A5);
    k_gate_out      <<<NPIX/64, 256, 0, stream>>>(A5, W_out, A4, A1);
    k_dw3<true,false><<<NPIX*64/256,256, 0, stream>>>(A1, w_odw1, nullptr, A2);
    k_dw3<false,true><<<NPIX*64/256,256, 0, stream>>>(A2, w_odw2, A1, out);
}

// Round 6
// 411.989 us; speedup vs baseline: 1.8027x; 1.0258x over previous
//
#include <hip/hip_runtime.h>
#include <hip/hip_bf16.h>
#include <math.h>

#define B_   4
#define H_   128
#define W_   128
#define C_   64
#define L_   (H_*W_)        // 16384 per batch
#define NPIX (B_*L_)        // 65536
#define DI_  128
#define NST  16
#define RT   4
#define TCH  64             // scan chunk length
#define NC   (L_/TCH)       // 256 chunks per batch

__device__ __forceinline__ float gelu_f(float x){
    return 0.5f*x*(1.f+erff(x*0.70710678118654752f));
}
__device__ __forceinline__ float silu_f(float x){
    return x/(1.f+__expf(-x));
}

// ---------------- fused LayerNorm + pw1 (register-tiled 4x4)
__global__ void k_lnpw(const float* __restrict__ x, const float* __restrict__ g,
                       const float* __restrict__ b, const float* __restrict__ W,
                       float* __restrict__ out){
    __shared__ float xl[64*65];
    __shared__ float Wt[64*65];    // Wt[c*65+o] = W[o*64+c]
    int tid = threadIdx.x;
    for (int i=tid;i<4096;i+=256){ int o=i>>6, c=i&63; Wt[c*65+o]=W[i]; }
    size_t base = (size_t)blockIdx.x*64*64;
    int c  = tid&63;
    int pr = tid>>6;
    float gc=g[c], bc=b[c];
    for (int p=pr;p<64;p+=4){
        float v = x[base + p*64 + c];
        float s=v, s2=v*v;
        #pragma unroll
        for (int off=32; off; off>>=1){
            s  += __shfl_xor(s,  off, 64);
            s2 += __shfl_xor(s2, off, 64);
        }
        float mu = s*(1.f/64.f);
        float var= s2*(1.f/64.f) - mu*mu;
        float r  = rsqrtf(var + 1e-5f);
        xl[p*65+c] = (v-mu)*r*gc + bc;
    }
    __syncthreads();
    int og=(tid&15)*4, pg=(tid>>4)*4;
    float acc[4][4]={};
    for (int cc=0;cc<64;cc++){
        float bv[4], av[4];
        #pragma unroll
        for (int j=0;j<4;j++) bv[j]=Wt[cc*65+og+j];
        #pragma unroll
        for (int i=0;i<4;i++) av[i]=xl[(pg+i)*65+cc];
        #pragma unroll
        for (int i=0;i<4;i++)
            #pragma unroll
            for (int j=0;j<4;j++) acc[i][j]+=av[i]*bv[j];
    }
    #pragma unroll
    for (int i=0;i<4;i++){
        float4 v4 = {acc[i][0],acc[i][1],acc[i][2],acc[i][3]};
        *(float4*)(out + base + (pg+i)*64 + og) = v4;
    }
}

// ---------------- pointwise 64x64 (register-tiled 4x4)
__global__ void k_pw(const float* __restrict__ in, const float* __restrict__ W,
                     float* __restrict__ out){
    __shared__ float xl[64*65];
    __shared__ float Wt[64*65];
    int tid = threadIdx.x;
    for (int i=tid;i<4096;i+=256){ int o=i>>6, c=i&63; Wt[c*65+o]=W[i]; }
    size_t base = (size_t)blockIdx.x*64*64;
    for (int i=tid;i<4096;i+=256) xl[(i>>6)*65+(i&63)]=in[base+i];
    __syncthreads();
    int og=(tid&15)*4, pg=(tid>>4)*4;
    float acc[4][4]={};
    for (int cc=0;cc<64;cc++){
        float bv[4], av[4];
        #pragma unroll
        for (int j=0;j<4;j++) bv[j]=Wt[cc*65+og+j];
        #pragma unroll
        for (int i=0;i<4;i++) av[i]=xl[(pg+i)*65+cc];
        #pragma unroll
        for (int i=0;i<4;i++)
            #pragma unroll
            for (int j=0;j<4;j++) acc[i][j]+=av[i]*bv[j];
    }
    #pragma unroll
    for (int i=0;i<4;i++){
        float4 v4 = {acc[i][0],acc[i][1],acc[i][2],acc[i][3]};
        *(float4*)(out + base + (pg+i)*64 + og) = v4;
    }
}

// ---------------- depthwise 3x3 SAME (NHWC), optional exact-GELU, optional residual add
template<bool GELU, bool ADDRES>
__global__ void k_dw3(const float* __restrict__ in, const float* __restrict__ w9,
                      const float* __restrict__ res, float* __restrict__ out){
    int idx = blockIdx.x*256 + threadIdx.x;   // over NPIX*64
    int c = idx & 63;
    int p = idx >> 6;
    int j = p & (W_-1);
    int t = p >> 7;       // b*H + i   (W_=128)
    int i = t & (H_-1);
    int b = t >> 7;       // H_=128
    float acc = 0.f;
    #pragma unroll
    for (int ki=0;ki<3;ki++){
        int ii = i + ki - 1;
        if (ii<0||ii>=H_) continue;
        #pragma unroll
        for (int kj=0;kj<3;kj++){
            int jj = j + kj - 1;
            if (jj<0||jj>=W_) continue;
            acc += in[(((b*H_+ii)*W_+jj)<<6)+c]*w9[c*9+ki*3+kj];
        }
    }
    if (GELU)   acc = gelu_f(acc);
    if (ADDRES) acc += res[idx];
    out[idx] = acc;
}

// ---------------- in-projection: 64 px/block, o-half per blockIdx.y, 8x4 tiles
__global__ void k_inproj(const float* __restrict__ x0, const float* __restrict__ W,
                         float* __restrict__ xs, float* __restrict__ z){
    __shared__ float xl[64*65];
    __shared__ float Wt[64*129];   // Wt[c*129+o'] = Wh[o'*64+c], o' in half
    int tid=threadIdx.x;
    const float* Wh = W + (size_t)blockIdx.y*128*64;
    for (int i=tid;i<8192;i+=256){ int o=i>>6, c=i&63; Wt[c*129+o]=Wh[i]; }
    size_t base=(size_t)blockIdx.x*64*64;
    for (int i=tid;i<4096;i+=256) xl[(i>>6)*65+(i&63)]=x0[base+i];
    __syncthreads();
    int og=(tid>>3)*4;    // 0..124
    int pg=(tid&7)*8;     // 0..56
    float acc[8][4]={};
    for (int cc=0;cc<64;cc++){
        float bv[4];
        #pragma unroll
        for (int j=0;j<4;j++) bv[j]=Wt[cc*129+og+j];
        #pragma unroll
        for (int i=0;i<8;i++){
            float av=xl[(pg+i)*65+cc];
            #pragma unroll
            for (int j=0;j<4;j++) acc[i][j]+=av*bv[j];
        }
    }
    size_t prow=(size_t)blockIdx.x*64;
    float* dst = blockIdx.y ? z : xs;
    #pragma unroll
    for (int i=0;i<8;i++){
        float4 v4={acc[i][0],acc[i][1],acc[i][2],acc[i][3]};
        *(float4*)(dst + (prow+pg+i)*DI_ + og) = v4;
    }
}

// ---------------- fused conv1d(k=4)+SiLU + xproj: outputs dtr (rank-4), Bm, Cm
// 256 thr, 64 px (one scan-chunk) per block. W staged in LDS (broadcast reads).
__global__ void k_xproj(const float* __restrict__ xs, const float* __restrict__ cw,
                        const float* __restrict__ cb, const float* __restrict__ Wx,
                        float* __restrict__ dtrO, float* __restrict__ Bm,
                        float* __restrict__ Cm){
    __shared__ float ul[64*128];    // [px][d] f4-col swizzled: slot = (d>>2)^(px&7)
    __shared__ float Wxl[36*128];   // [j][d] rows, read via uniform b128 (broadcast)
    __shared__ float sOut[64*37];   // [px][j]
    int tid=threadIdx.x;   // 256
    int blk=blockIdx.x;    // b*NC + chunk
    int b  = blk >> 8;
    int l0 = (blk & 255)*64;
    for (int i=tid;i<1152;i+=256) ((float4*)Wxl)[i] = ((const float4*)Wx)[i];
    // phase 1: rolling-window conv + silu -> ul (swizzled)
    {
        int d = tid&127, pxg=(tid>>7)*32;
        float4 cw4=*(const float4*)(cw+d*4); float cbd=cb[d];
        const float* xsp = xs + ((size_t)b*L_+l0+pxg)*DI_ + d;
        float w0=0.f,w1=0.f,w2=0.f;
        if (l0+pxg>0){ w0=xsp[-3*DI_]; w1=xsp[-2*DI_]; w2=xsp[-1*DI_]; }
        #pragma unroll 8
        for (int q=0;q<32;q++){
            float xc = xsp[q*DI_];
            float sv = cbd + w0*cw4.x + w1*cw4.y + w2*cw4.z + xc*cw4.w;
            float uv = sv/(1.f+__expf(-sv));
            w0=w1; w1=w2; w2=xc;
            int px = pxg+q;
            ul[px*128 + (((d>>2)^(px&7))<<2) + (d&3)] = uv;
        }
    }
    __syncthreads();
    // phase 2: 64px x 36out GEMM, K=128. A: 1 lane b128; W: 9 uniform b128 (broadcast).
    {
        int px = tid & 63;
        int og = __builtin_amdgcn_readfirstlane(tid >> 6);   // 0..3, wave-uniform
        float acc[9]={};
        const float4* ul4 = (const float4*)ul;
        for (int d4=0; d4<32; d4++){
            float4 a = ul4[px*32 + (d4 ^ (px&7))];
            #pragma unroll
            for (int k2=0;k2<9;k2++){
                const float4 w = ((const float4*)(Wxl+(og+k2*4)*128))[d4];
                acc[k2] += a.x*w.x + a.y*w.y + a.z*w.z + a.w*w.w;
            }
        }
        #pragma unroll
        for (int k2=0;k2<9;k2++) sOut[px*37 + og + k2*4] = acc[k2];
    }
    __syncthreads();
    size_t pbase=(size_t)blk*64;
    for (int i=tid;i<1024;i+=256){
        int p=i>>4, s=i&15;
        Bm[(pbase+p)*NST+s] = sOut[p*37+RT+s];
        Cm[(pbase+p)*NST+s] = sOut[p*37+RT+NST+s];
    }
    if (tid<256) dtrO[pbase*4+tid] = sOut[(tid>>2)*37+(tid&3)];
}

// ---------------- scan pass A: 512 thr, thread=(sg,d); conv+dt recomputed on the fly
#define SLGA(X,t0) _Pragma("unroll") for(int q=0;q<8;q++){ X[q]=xsp[((t0)+q)*DI_]; }
#define SSTA(X,t0) _Pragma("unroll") for(int q=0;q<8;q++){ \
    float xc=X[q]; \
    float sv = cbd + w0*cw4.x + w1*cw4.y + w2*cw4.z + xc*cw4.w; \
    float uv = sv/(1.f+__expf(-sv)); \
    w0=w1; w1=w2; w2=xc; \
    const float4 dr=*(const float4*)(dtrl+((t0)+q)*4); \
    float tt = dr.x*wd.x + dr.y*wd.y + dr.z*wd.z + dr.w*wd.w + bd; \
    float dtv = (tt>20.f)? tt : __logf(1.f+__expf(tt)); \
    sd += dtv; float du = dtv*uv; \
    const float4 Bv=*(const float4*)(Bl+((t0)+q)*NST+sg*4); \
    h0=__expf(dtv*A0)*h0+du*Bv.x; h1=__expf(dtv*A1)*h1+du*Bv.y; \
    h2=__expf(dtv*A2)*h2+du*Bv.z; h3=__expf(dtv*A3)*h3+du*Bv.w; }

__global__ void k_scanA(const float* __restrict__ xs, const float* __restrict__ cw,
                        const float* __restrict__ cb, const float* __restrict__ dtr,
                        const float* __restrict__ Wdt, const float* __restrict__ bdt,
                        const float* __restrict__ Bm, const float* __restrict__ Alog,
                        float* __restrict__ E, float* __restrict__ sumdt){
    __shared__ float Bl[TCH*NST];
    __shared__ float dtrl[TCH*4];
    int tid=threadIdx.x;       // 512
    int blk=blockIdx.x;
    int b = blk >> 8;
    int k = blk & 255;
    int l0 = k*TCH;
    for (int i=tid;i<TCH*NST;i+=512) Bl[i]=Bm[((size_t)b*L_+l0)*NST+i];
    if (tid<256) dtrl[tid]=dtr[((size_t)b*L_+l0)*4+tid];
    __syncthreads();
    int sg = tid >> 7;         // 0..3
    int d  = tid & 127;
    float4 al = *(const float4*)(Alog + d*NST + sg*4);
    float A0=-__expf(al.x), A1=-__expf(al.y), A2=-__expf(al.z), A3=-__expf(al.w);
    float4 cw4=*(const float4*)(cw+d*4); float cbd=cb[d];
    float4 wd =*(const float4*)(Wdt+d*4); float bd=bdt[d];
    const float* xsp = xs + ((size_t)b*L_+l0)*DI_ + d;
    float w0=0.f,w1=0.f,w2=0.f;
    if (l0>0){ w0=xsp[-3*DI_]; w1=xsp[-2*DI_]; w2=xsp[-1*DI_]; }
    float h0=0.f,h1=0.f,h2=0.f,h3=0.f,sd=0.f;
    float xA[8],xB[8];
    SLGA(xA,0);
    for (int t0=0;t0<TCH;t0+=16){
        SLGA(xB,t0+8);
        SSTA(xA,t0);
        if (t0+16<TCH){ SLGA(xA,t0+16); }
        SSTA(xB,t0+8);
    }
    float4 hv = {h0,h1,h2,h3};
    *(float4*)(E + ((size_t)blk*DI_+d)*NST + sg*4) = hv;
    if (sg==0) sumdt[(size_t)blk*DI_+d]=sd;
}

// ---------------- scan pass B: chunk-level recurrence, 8-deep prefetch
#define LGB(EB,SB,kk) _Pragma("unroll") for(int q=0;q<8;q++){ \
    size_t base=((size_t)(b*NC+(kk)+q)*DI_+d); EB[q]=E[base*NST+s]; SB[q]=sumdt[base]; }
#define STB(EB,SB,kk) _Pragma("unroll") for(int q=0;q<8;q++){ \
    size_t base=((size_t)(b*NC+(kk)+q)*DI_+d); Hst[base*NST+s]=h; \
    h = __expf(Av*SB[q])*h + EB[q]; }

__global__ void k_scanB(const float* __restrict__ E, const float* __restrict__ sumdt,
                        const float* __restrict__ Alog, float* __restrict__ Hst){
    int idx = blockIdx.x*256+threadIdx.x;  // B*DI*NST = 8192
    if (idx >= B_*DI_*NST) return;
    int s = idx & 15;
    int d = (idx>>4) & 127;
    int b = idx >> 11;
    float Av = -__expf(Alog[d*NST+s]);
    float h = 0.f;
    float eA[8],sA[8],eB[8],sB[8];
    LGB(eA,sA,0);
    for (int k=0;k<NC;k+=16){
        LGB(eB,sB,k+8);
        STB(eA,sA,k);
        if (k+16<NC){ LGB(eA,sA,k+16); }
        STB(eB,sB,k+8);
    }
}

// ---------------- scan pass C: 512 thr, thread=(d,sg); conv+dt on the fly; writes gated v
#define SLGC(X,Z,t0) _Pragma("unroll") for(int q=0;q<8;q++){ \
    X[q]=xsp[((t0)+q)*DI_]; Z[q]=zp[((t0)+q)*DI_]; }
#define SSTC(X,Z,t0) _Pragma("unroll") for(int q=0;q<8;q++){ \
    float xc=X[q]; \
    float sv = cbd + w0*cw4.x + w1*cw4.y + w2*cw4.z + xc*cw4.w; \
    float uv = sv/(1.f+__expf(-sv)); \
    w0=w1; w1=w2; w2=xc; \
    const float4 dr=*(const float4*)(dtrl+((t0)+q)*4); \
    float tt = dr.x*wd.x + dr.y*wd.y + dr.z*wd.z + dr.w*wd.w + bd; \
    float dtv = (tt>20.f)? tt : __logf(1.f+__expf(tt)); \
    float du = dtv*uv; \
    const float4 Bv=*(const float4*)(Bl+((t0)+q)*NST+sg*4); \
    const float4 Cv=*(const float4*)(Cl+((t0)+q)*NST+sg*4); \
    float yv; \
    h0=__expf(dtv*A0)*h0+du*Bv.x; yv =h0*Cv.x; \
    h1=__expf(dtv*A1)*h1+du*Bv.y; yv+=h1*Cv.y; \
    h2=__expf(dtv*A2)*h2+du*Bv.z; yv+=h2*Cv.z; \
    h3=__expf(dtv*A3)*h3+du*Bv.w; yv+=h3*Cv.w; \
    yv += __shfl_xor(yv,1,64); yv += __shfl_xor(yv,2,64); \
    if (sg==0) vp[((t0)+q)*DI_] = (yv + uv*Dd)*silu_f(Z[q]); }

__global__ void k_scanC(const float* __restrict__ xs, const float* __restrict__ cw,
                        const float* __restrict__ cb, const float* __restrict__ dtr,
                        const float* __restrict__ Wdt, const float* __restrict__ bdt,
                        const float* __restrict__ Bm, const float* __restrict__ Cm,
                        const float* __restrict__ Alog, const float* __restrict__ Hst,
                        const float* __restrict__ z, const float* __restrict__ Dv,
                        float* __restrict__ v){
    __shared__ float Bl[TCH*NST];
    __shared__ float Cl[TCH*NST];
    __shared__ float dtrl[TCH*4];
    int tid=threadIdx.x;   // 512
    int blk=blockIdx.x;
    int b = blk >> 8;
    int k = blk & 255;
    int l0 = k*TCH;
    for (int i=tid;i<TCH*NST;i+=512){
        Bl[i]=Bm[((size_t)b*L_+l0)*NST+i];
        Cl[i]=Cm[((size_t)b*L_+l0)*NST+i];
    }
    if (tid<256) dtrl[tid]=dtr[((size_t)b*L_+l0)*4+tid];
    __syncthreads();
    int d  = tid >> 2;     // 0..127
    int sg = tid & 3;
    float4 al = *(const float4*)(Alog + d*NST + sg*4);
    float A0=-__expf(al.x), A1=-__expf(al.y), A2=-__expf(al.z), A3=-__expf(al.w);
    float4 hv = *(const float4*)(Hst + ((size_t)blk*DI_+d)*NST + sg*4);
    float h0=hv.x,h1=hv.y,h2=hv.z,h3=hv.w;
    float4 cw4=*(const float4*)(cw+d*4); float cbd=cb[d];
    float4 wd =*(const float4*)(Wdt+d*4); float bd=bdt[d];
    const float* xsp = xs + ((size_t)b*L_+l0)*DI_ + d;
    const float* zp  = z  + ((size_t)b*L_+l0)*DI_ + d;
    float* vp = v + ((size_t)b*L_+l0)*DI_ + d;
    float Dd = Dv[d];
    float w0=0.f,w1=0.f,w2=0.f;
    if (l0>0){ w0=xsp[-3*DI_]; w1=xsp[-2*DI_]; w2=xsp[-1*DI_]; }
    float xA[8],zA[8],xB[8],zB[8];
    SLGC(xA,zA,0);
    for (int t0=0;t0<TCH;t0+=16){
        SLGC(xB,zB,t0+8);
        SSTC(xA,zA,t0);
        if (t0+16<TCH){ SLGC(xA,zA,t0+16); }
        SSTC(xB,zB,t0+8);
    }
}

// ---------------- gate GEMM: x1 = v @ Wout^T + x0 ; 64 px/block, 256 thr, 4x4 tiles
__global__ void k_gate_out(const float* __restrict__ v, const float* __restrict__ Wout,
                           const float* __restrict__ x0, float* __restrict__ x1){
    __shared__ float vl[64*132];   // [p][d]
    __shared__ float Wl[64*132];   // [o][d]
    int tid=threadIdx.x;   // 256
    size_t pbase=(size_t)blockIdx.x*64;
    for (int i=tid;i<2048;i+=256){ int o=i>>5, dq=i&31;
        ((float4*)(Wl+o*132))[dq] = ((const float4*)(Wout+o*DI_))[dq]; }
    for (int i=tid;i<2048;i+=256){ int p=i>>5, dq=i&31;
        ((float4*)(vl+p*132))[dq] = ((const float4*)(v+(pbase+p)*DI_))[dq]; }
    __syncthreads();
    int og=(tid&15)*4, pg=(tid>>4)*4;
    float acc[4][4]={};
    for (int d4=0; d4<32; d4++){
        float4 wv[4], av[4];
        #pragma unroll
        for (int j=0;j<4;j++) wv[j]=((const float4*)(Wl+(og+j)*132))[d4];
        #pragma unroll
        for (int i=0;i<4;i++) av[i]=((const float4*)(vl+(pg+i)*132))[d4];
        #pragma unroll
        for (int i=0;i<4;i++)
            #pragma unroll
            for (int j=0;j<4;j++)
                acc[i][j] += av[i].x*wv[j].x + av[i].y*wv[j].y
                           + av[i].z*wv[j].z + av[i].w*wv[j].w;
    }
    #pragma unroll
    for (int i=0;i<4;i++){
        size_t gi=(pbase+pg+i)*64+og;
        float4 r=*(const float4*)(x0+gi);
        float4 o4={acc[i][0]+r.x, acc[i][1]+r.y, acc[i][2]+r.z, acc[i][3]+r.w};
        *(float4*)(x1+gi)=o4;
    }
}

extern "C" void kernel_launch(void* const* d_in, const int* in_sizes, int n_in,
                              void* d_out, int out_size, void* d_ws, size_t ws_size,
                              hipStream_t stream){
    const float* x      = (const float*)d_in[0];
    const float* ln_g   = (const float*)d_in[1];
    const float* ln_b   = (const float*)d_in[2];
    const float* w_pw1  = (const float*)d_in[3];
    const float* w_dw   = (const float*)d_in[4];
    const float* w_pw2  = (const float*)d_in[5];
    const float* w_odw1 = (const float*)d_in[6];
    const float* w_odw2 = (const float*)d_in[7];
    const float* W_inpj = (const float*)d_in[8];
    const float* conv_w = (const float*)d_in[9];
    const float* conv_b = (const float*)d_in[10];
    const float* W_xprj = (const float*)d_in[11];
    const float* W_dt   = (const float*)d_in[12];
    const float* b_dt   = (const float*)d_in[13];
    const float* A_log  = (const float*)d_in[14];
    const float* Dvec   = (const float*)d_in[15];
    const float* W_out  = (const float*)d_in[16];
    float* out = (float*)d_out;

    char* ws = (char*)d_ws;
    const size_t SZ64  = (size_t)NPIX*64*4;    // 16 MiB
    const size_t SZ128 = (size_t)NPIX*128*4;   // 32 MiB
    float* A1 = (float*)(ws);                  // x1
    float* A2 = (float*)(ws + SZ64);           // t1 -> {E,sumdt} -> t3
    float* A3 = (float*)(ws + 2*SZ64);         // t2 -> {Bm,Cm,Hst}
    float* A4 = (float*)(ws + 3*SZ64);         // x0
    float* A5 = (float*)(ws + 4*SZ64);         // xs
    float* A6 = (float*)(ws + 4*SZ64 + SZ128); // z
    float* A7 = (float*)(ws + 4*SZ64 + 2*SZ128); // v
    float* A8 = (float*)(ws + 4*SZ64 + 3*SZ128); // dtr (1 MiB)
    float* Ebuf  = A2;
    float* sumdt = (float*)((char*)A2 + (size_t)B_*NC*DI_*NST*4);
    float* Bmb = A3;
    float* Cmb = (float*)((char*)A3 + (size_t)NPIX*NST*4);
    float* Hst = (float*)((char*)A3 + (size_t)2*NPIX*NST*4);

    k_lnpw          <<<NPIX/64, 256, 0, stream>>>(x, ln_g, ln_b, w_pw1, A2);
    k_dw3<true,false><<<NPIX*64/256,256, 0, stream>>>(A2, w_dw, nullptr, A3);
    k_pw            <<<NPIX/64, 256, 0, stream>>>(A3, w_pw2, A4);
    k_inproj        <<<dim3(NPIX/64,2), 256, 0, stream>>>(A4, W_inpj, A5, A6);
    k_xproj         <<<B_*NC,   256, 0, stream>>>(A5, conv_w, conv_b, W_xprj,
                                                  A8, Bmb, Cmb);
    k_scanA         <<<B_*NC,   512, 0, stream>>>(A5, conv_w, conv_b, A8, W_dt, b_dt,
                                                  Bmb, A_log, Ebuf, sumdt);
    k_scanB         <<<32,      256, 0, stream>>>(Ebuf, sumdt, A_log, Hst);
    k_scanC         <<<B_*NC,   512, 0, stream>>>(A5, conv_w, conv_b, A8, W_dt, b_dt,
                                                  Bmb, Cmb, A_log, Hst, A6, Dvec, A7);
    k_gate_out      <<<NPIX/64, 256, 0, stream>>>(A7, W_out, A4, A1);
    k_dw3<true,false><<<NPIX*64/256,256, 0, stream>>>(A1, w_odw1, nullptr, A2);
    k_dw3<false,true><<<NPIX*64/256,256, 0, stream>>>(A2, w_odw2, A1, out);
}

// Round 7
// 359.486 us; speedup vs baseline: 2.0659x; 1.1461x over previous
//
#include <hip/hip_runtime.h>
#include <hip/hip_bf16.h>
#include <math.h>

#define B_   4
#define H_   128
#define W_   128
#define C_   64
#define L_   (H_*W_)        // 16384 per batch
#define NPIX (B_*L_)        // 65536
#define DI_  128
#define NST  16
#define RT   4
#define TCH  64             // scan chunk length
#define NC   (L_/TCH)       // 256 chunks per batch

__device__ __forceinline__ float gelu_f(float x){
    return 0.5f*x*(1.f+erff(x*0.70710678118654752f));
}
__device__ __forceinline__ float silu_f(float x){
    return x/(1.f+__expf(-x));
}

// ---------------- fused LayerNorm + pw1 (register-tiled 4x4)
__global__ void k_lnpw(const float* __restrict__ x, const float* __restrict__ g,
                       const float* __restrict__ b, const float* __restrict__ W,
                       float* __restrict__ out){
    __shared__ float xl[64*65];
    __shared__ float Wt[64*65];    // Wt[c*65+o] = W[o*64+c]
    int tid = threadIdx.x;
    for (int i=tid;i<4096;i+=256){ int o=i>>6, c=i&63; Wt[c*65+o]=W[i]; }
    size_t base = (size_t)blockIdx.x*64*64;
    int c  = tid&63;
    int pr = tid>>6;
    float gc=g[c], bc=b[c];
    for (int p=pr;p<64;p+=4){
        float v = x[base + p*64 + c];
        float s=v, s2=v*v;
        #pragma unroll
        for (int off=32; off; off>>=1){
            s  += __shfl_xor(s,  off, 64);
            s2 += __shfl_xor(s2, off, 64);
        }
        float mu = s*(1.f/64.f);
        float var= s2*(1.f/64.f) - mu*mu;
        float r  = rsqrtf(var + 1e-5f);
        xl[p*65+c] = (v-mu)*r*gc + bc;
    }
    __syncthreads();
    int og=(tid&15)*4, pg=(tid>>4)*4;
    float acc[4][4]={};
    for (int cc=0;cc<64;cc++){
        float bv[4], av[4];
        #pragma unroll
        for (int j=0;j<4;j++) bv[j]=Wt[cc*65+og+j];
        #pragma unroll
        for (int i=0;i<4;i++) av[i]=xl[(pg+i)*65+cc];
        #pragma unroll
        for (int i=0;i<4;i++)
            #pragma unroll
            for (int j=0;j<4;j++) acc[i][j]+=av[i]*bv[j];
    }
    #pragma unroll
    for (int i=0;i<4;i++){
        float4 v4 = {acc[i][0],acc[i][1],acc[i][2],acc[i][3]};
        *(float4*)(out + base + (pg+i)*64 + og) = v4;
    }
}

// ---------------- pointwise 64x64 (register-tiled 4x4)
__global__ void k_pw(const float* __restrict__ in, const float* __restrict__ W,
                     float* __restrict__ out){
    __shared__ float xl[64*65];
    __shared__ float Wt[64*65];
    int tid = threadIdx.x;
    for (int i=tid;i<4096;i+=256){ int o=i>>6, c=i&63; Wt[c*65+o]=W[i]; }
    size_t base = (size_t)blockIdx.x*64*64;
    for (int i=tid;i<4096;i+=256) xl[(i>>6)*65+(i&63)]=in[base+i];
    __syncthreads();
    int og=(tid&15)*4, pg=(tid>>4)*4;
    float acc[4][4]={};
    for (int cc=0;cc<64;cc++){
        float bv[4], av[4];
        #pragma unroll
        for (int j=0;j<4;j++) bv[j]=Wt[cc*65+og+j];
        #pragma unroll
        for (int i=0;i<4;i++) av[i]=xl[(pg+i)*65+cc];
        #pragma unroll
        for (int i=0;i<4;i++)
            #pragma unroll
            for (int j=0;j<4;j++) acc[i][j]+=av[i]*bv[j];
    }
    #pragma unroll
    for (int i=0;i<4;i++){
        float4 v4 = {acc[i][0],acc[i][1],acc[i][2],acc[i][3]};
        *(float4*)(out + base + (pg+i)*64 + og) = v4;
    }
}

// ---------------- depthwise 3x3 SAME (NHWC), optional exact-GELU, optional residual add
template<bool GELU, bool ADDRES>
__global__ void k_dw3(const float* __restrict__ in, const float* __restrict__ w9,
                      const float* __restrict__ res, float* __restrict__ out){
    int idx = blockIdx.x*256 + threadIdx.x;   // over NPIX*64
    int c = idx & 63;
    int p = idx >> 6;
    int j = p & (W_-1);
    int t = p >> 7;       // b*H + i   (W_=128)
    int i = t & (H_-1);
    int b = t >> 7;       // H_=128
    float acc = 0.f;
    #pragma unroll
    for (int ki=0;ki<3;ki++){
        int ii = i + ki - 1;
        if (ii<0||ii>=H_) continue;
        #pragma unroll
        for (int kj=0;kj<3;kj++){
            int jj = j + kj - 1;
            if (jj<0||jj>=W_) continue;
            acc += in[(((b*H_+ii)*W_+jj)<<6)+c]*w9[c*9+ki*3+kj];
        }
    }
    if (GELU)   acc = gelu_f(acc);
    if (ADDRES) acc += res[idx];
    out[idx] = acc;
}

// ---------------- in-projection: 64 px/block, o-half per blockIdx.y, 8x4 tiles
__global__ void k_inproj(const float* __restrict__ x0, const float* __restrict__ W,
                         float* __restrict__ xs, float* __restrict__ z){
    __shared__ float xl[64*65];
    __shared__ float Wt[64*129];   // Wt[c*129+o'] = Wh[o'*64+c], o' in half
    int tid=threadIdx.x;
    const float* Wh = W + (size_t)blockIdx.y*128*64;
    for (int i=tid;i<8192;i+=256){ int o=i>>6, c=i&63; Wt[c*129+o]=Wh[i]; }
    size_t base=(size_t)blockIdx.x*64*64;
    for (int i=tid;i<4096;i+=256) xl[(i>>6)*65+(i&63)]=x0[base+i];
    __syncthreads();
    int og=(tid>>3)*4;    // 0..124
    int pg=(tid&7)*8;     // 0..56
    float acc[8][4]={};
    for (int cc=0;cc<64;cc++){
        float bv[4];
        #pragma unroll
        for (int j=0;j<4;j++) bv[j]=Wt[cc*129+og+j];
        #pragma unroll
        for (int i=0;i<8;i++){
            float av=xl[(pg+i)*65+cc];
            #pragma unroll
            for (int j=0;j<4;j++) acc[i][j]+=av*bv[j];
        }
    }
    size_t prow=(size_t)blockIdx.x*64;
    float* dst = blockIdx.y ? z : xs;
    #pragma unroll
    for (int i=0;i<8;i++){
        float4 v4={acc[i][0],acc[i][1],acc[i][2],acc[i][3]};
        *(float4*)(dst + (prow+pg+i)*DI_ + og) = v4;
    }
}

// ---------------- fused conv1d(k=4)+SiLU + xproj: outputs dtr (rank-4), Bm, Cm
__global__ void k_xproj(const float* __restrict__ xs, const float* __restrict__ cw,
                        const float* __restrict__ cb, const float* __restrict__ Wx,
                        float* __restrict__ dtrO, float* __restrict__ Bm,
                        float* __restrict__ Cm){
    __shared__ float ul[64*128];    // [px][d] f4-col swizzled: slot = (d>>2)^(px&7)
    __shared__ float Wxl[36*128];   // [j][d] rows, read via uniform b128 (broadcast)
    __shared__ float sOut[64*37];   // [px][j]
    int tid=threadIdx.x;   // 256
    int blk=blockIdx.x;    // b*NC + chunk
    int b  = blk >> 8;
    int l0 = (blk & 255)*64;
    for (int i=tid;i<1152;i+=256) ((float4*)Wxl)[i] = ((const float4*)Wx)[i];
    // phase 1: rolling-window conv + silu -> ul (swizzled)
    {
        int d = tid&127, pxg=(tid>>7)*32;
        float4 cw4=*(const float4*)(cw+d*4); float cbd=cb[d];
        const float* xsp = xs + ((size_t)b*L_+l0+pxg)*DI_ + d;
        float w0=0.f,w1=0.f,w2=0.f;
        if (l0+pxg>0){ w0=xsp[-3*DI_]; w1=xsp[-2*DI_]; w2=xsp[-1*DI_]; }
        #pragma unroll 8
        for (int q=0;q<32;q++){
            float xc = xsp[q*DI_];
            float sv = cbd + w0*cw4.x + w1*cw4.y + w2*cw4.z + xc*cw4.w;
            float uv = sv/(1.f+__expf(-sv));
            w0=w1; w1=w2; w2=xc;
            int px = pxg+q;
            ul[px*128 + (((d>>2)^(px&7))<<2) + (d&3)] = uv;
        }
    }
    __syncthreads();
    // phase 2: 64px x 36out GEMM, K=128.
    {
        int px = tid & 63;
        int og = __builtin_amdgcn_readfirstlane(tid >> 6);   // 0..3, wave-uniform
        float acc[9]={};
        const float4* ul4 = (const float4*)ul;
        for (int d4=0; d4<32; d4++){
            float4 a = ul4[px*32 + (d4 ^ (px&7))];
            #pragma unroll
            for (int k2=0;k2<9;k2++){
                const float4 w = ((const float4*)(Wxl+(og+k2*4)*128))[d4];
                acc[k2] += a.x*w.x + a.y*w.y + a.z*w.z + a.w*w.w;
            }
        }
        #pragma unroll
        for (int k2=0;k2<9;k2++) sOut[px*37 + og + k2*4] = acc[k2];
    }
    __syncthreads();
    size_t pbase=(size_t)blk*64;
    for (int i=tid;i<1024;i+=256){
        int p=i>>4, s=i&15;
        Bm[(pbase+p)*NST+s] = sOut[p*37+RT+s];
        Cm[(pbase+p)*NST+s] = sOut[p*37+RT+NST+s];
    }
    if (tid<256) dtrO[pbase*4+tid] = sOut[(tid>>2)*37+(tid&3)];
}

// ---------------- shared phase-0: compute u,dt ONCE per (t,d) into LDS
__device__ __forceinline__ void stage_udt(const float* __restrict__ xs,
                                          const float* __restrict__ cw,
                                          const float* __restrict__ cb,
                                          const float* __restrict__ Wdt,
                                          const float* __restrict__ bdt,
                                          const float* __restrict__ dtrl,
                                          float* ul, float* dtl,
                                          int b, int l0, int tid){
    int d  = tid & 127;
    int tg = tid >> 7;            // 0..3
    int t0 = tg*16;
    float4 cw4=*(const float4*)(cw+d*4); float cbd=cb[d];
    float4 wd =*(const float4*)(Wdt+d*4); float bd=bdt[d];
    const float* xsp = xs + ((size_t)b*L_+l0+t0)*DI_ + d;
    float w0=0.f,w1=0.f,w2=0.f;
    if (l0+t0>0){ w0=xsp[-3*DI_]; w1=xsp[-2*DI_]; w2=xsp[-1*DI_]; }
    #pragma unroll
    for (int q=0;q<16;q++){
        float xc = xsp[q*DI_];
        float sv = cbd + w0*cw4.x + w1*cw4.y + w2*cw4.z + xc*cw4.w;
        float uv = sv/(1.f+__expf(-sv));
        w0=w1; w1=w2; w2=xc;
        int t = t0+q;
        const float4 dr = *(const float4*)(dtrl+t*4);
        float tt = dr.x*wd.x + dr.y*wd.y + dr.z*wd.z + dr.w*wd.w + bd;
        float dtv = (tt>20.f)? tt : __logf(1.f+__expf(tt));
        ul[t*128+d]  = uv;
        dtl[t*128+d] = dtv;
    }
}

// ---------------- scan pass A: phase0 LDS staging + tight recurrence
// E layout: [blk][sg][d][4]
__global__ void k_scanA(const float* __restrict__ xs, const float* __restrict__ cw,
                        const float* __restrict__ cb, const float* __restrict__ dtr,
                        const float* __restrict__ Wdt, const float* __restrict__ bdt,
                        const float* __restrict__ Bm, const float* __restrict__ Alog,
                        float* __restrict__ E, float* __restrict__ sumdt){
    __shared__ float ul[TCH*128];
    __shared__ float dtl[TCH*128];
    __shared__ float Bl[TCH*NST];
    __shared__ float dtrl[TCH*4];
    int tid=threadIdx.x;       // 512
    int blk=blockIdx.x;
    int b = blk >> 8;
    int l0 = (blk & 255)*TCH;
    for (int i=tid;i<TCH*NST;i+=512) Bl[i]=Bm[((size_t)b*L_+l0)*NST+i];
    if (tid<TCH*4) dtrl[tid]=dtr[((size_t)b*L_+l0)*4+tid];
    __syncthreads();
    stage_udt(xs,cw,cb,Wdt,bdt,dtrl,ul,dtl,b,l0,tid);
    __syncthreads();
    int sg = tid >> 7;         // 0..3, wave-uniform
    int d  = tid & 127;
    float4 al = *(const float4*)(Alog + d*NST + sg*4);
    float A0=-__expf(al.x), A1=-__expf(al.y), A2=-__expf(al.z), A3=-__expf(al.w);
    float h0=0.f,h1=0.f,h2=0.f,h3=0.f,sd=0.f;
    #pragma unroll 8
    for (int t=0;t<TCH;t++){
        float dtv = dtl[t*128+d];
        float du  = dtv*ul[t*128+d];
        sd += dtv;
        const float4 Bv=*(const float4*)(Bl+t*NST+sg*4);
        h0=__expf(dtv*A0)*h0+du*Bv.x;
        h1=__expf(dtv*A1)*h1+du*Bv.y;
        h2=__expf(dtv*A2)*h2+du*Bv.z;
        h3=__expf(dtv*A3)*h3+du*Bv.w;
    }
    float4 hv = {h0,h1,h2,h3};
    *(float4*)(E + (((size_t)blk*4+sg)*128+d)*4) = hv;
    if (sg==0) sumdt[(size_t)blk*128+d]=sd;
}

// ---------------- scan pass B: chunk recurrence, named-scalar 4-deep prefetch
__global__ void k_scanB(const float* __restrict__ E, const float* __restrict__ sumdt,
                        const float* __restrict__ Alog, float* __restrict__ Hst){
    int idx = blockIdx.x*256+threadIdx.x;  // B*DI*NST = 8192
    if (idx >= B_*DI_*NST) return;
    int j  = idx & 3;
    int sg = (idx>>2) & 3;
    int d  = (idx>>4) & 127;
    int b  = idx >> 11;
    float Av = -__expf(Alog[d*NST+sg*4+j]);
    size_t eb = (((size_t)(b*NC)*4+sg)*128+d)*4+j;   // + k*2048
    size_t sb = (size_t)b*NC*128 + d;                // + k*128
    float h = 0.f;
    for (int k=0;k<NC;k+=4){
        float E0=E[eb+(size_t)k*2048],     S0=sumdt[sb+(size_t)k*128];
        float E1=E[eb+(size_t)(k+1)*2048], S1=sumdt[sb+(size_t)(k+1)*128];
        float E2=E[eb+(size_t)(k+2)*2048], S2=sumdt[sb+(size_t)(k+2)*128];
        float E3=E[eb+(size_t)(k+3)*2048], S3=sumdt[sb+(size_t)(k+3)*128];
        Hst[eb+(size_t)k*2048]=h;     h=__expf(Av*S0)*h+E0;
        Hst[eb+(size_t)(k+1)*2048]=h; h=__expf(Av*S1)*h+E1;
        Hst[eb+(size_t)(k+2)*2048]=h; h=__expf(Av*S2)*h+E2;
        Hst[eb+(size_t)(k+3)*2048]=h; h=__expf(Av*S3)*h+E3;
    }
}

// ---------------- scan pass C: phase0 staging + recurrence; writes y_raw = y + u*D
__global__ void k_scanC(const float* __restrict__ xs, const float* __restrict__ cw,
                        const float* __restrict__ cb, const float* __restrict__ dtr,
                        const float* __restrict__ Wdt, const float* __restrict__ bdt,
                        const float* __restrict__ Bm, const float* __restrict__ Cm,
                        const float* __restrict__ Alog, const float* __restrict__ Hst,
                        const float* __restrict__ Dv, float* __restrict__ yr){
    __shared__ float ul[TCH*128];
    __shared__ float dtl[TCH*128];
    __shared__ float Bl[TCH*NST];
    __shared__ float Cl[TCH*NST];
    __shared__ float dtrl[TCH*4];
    int tid=threadIdx.x;   // 512
    int blk=blockIdx.x;
    int b = blk >> 8;
    int l0 = (blk & 255)*TCH;
    for (int i=tid;i<TCH*NST;i+=512){
        Bl[i]=Bm[((size_t)b*L_+l0)*NST+i];
        Cl[i]=Cm[((size_t)b*L_+l0)*NST+i];
    }
    if (tid<TCH*4) dtrl[tid]=dtr[((size_t)b*L_+l0)*4+tid];
    __syncthreads();
    stage_udt(xs,cw,cb,Wdt,bdt,dtrl,ul,dtl,b,l0,tid);
    __syncthreads();
    int d  = tid >> 2;     // 0..127
    int sg = tid & 3;      // lane[1:0]
    float4 al = *(const float4*)(Alog + d*NST + sg*4);
    float A0=-__expf(al.x), A1=-__expf(al.y), A2=-__expf(al.z), A3=-__expf(al.w);
    float4 hv = *(const float4*)(Hst + (((size_t)blk*4+sg)*128+d)*4);
    float h0=hv.x,h1=hv.y,h2=hv.z,h3=hv.w;
    float Dd = Dv[d];
    float* yp = yr + ((size_t)b*L_+l0)*DI_ + d;
    #pragma unroll 4
    for (int t=0;t<TCH;t++){
        float dtv = dtl[t*128+d];
        float uv  = ul[t*128+d];
        float du  = dtv*uv;
        const float4 Bv=*(const float4*)(Bl+t*NST+sg*4);
        const float4 Cv=*(const float4*)(Cl+t*NST+sg*4);
        float yv;
        h0=__expf(dtv*A0)*h0+du*Bv.x; yv =h0*Cv.x;
        h1=__expf(dtv*A1)*h1+du*Bv.y; yv+=h1*Cv.y;
        h2=__expf(dtv*A2)*h2+du*Bv.z; yv+=h2*Cv.z;
        h3=__expf(dtv*A3)*h3+du*Bv.w; yv+=h3*Cv.w;
        yv += __shfl_xor(yv,1,4);      // quad-perm DPP
        yv += __shfl_xor(yv,2,4);
        if (sg==0) yp[t*DI_] = yv + uv*Dd;
    }
}

// ---------------- gate GEMM: x1 = (yr*silu(z)) @ Wout^T + x0
__global__ void k_gate_out(const float* __restrict__ yr, const float* __restrict__ z,
                           const float* __restrict__ Wout,
                           const float* __restrict__ x0, float* __restrict__ x1){
    __shared__ float vl[64*132];   // [p][d] gated value
    __shared__ float Wl[64*132];   // [o][d]
    int tid=threadIdx.x;   // 256
    size_t pbase=(size_t)blockIdx.x*64;
    for (int i=tid;i<2048;i+=256){ int o=i>>5, dq=i&31;
        ((float4*)(Wl+o*132))[dq] = ((const float4*)(Wout+o*DI_))[dq]; }
    for (int i=tid;i<2048;i+=256){ int p=i>>5, dq=i&31;
        float4 yv=((const float4*)(yr+(pbase+p)*DI_))[dq];
        float4 zv=((const float4*)(z +(pbase+p)*DI_))[dq];
        float4 gv={yv.x*silu_f(zv.x), yv.y*silu_f(zv.y),
                   yv.z*silu_f(zv.z), yv.w*silu_f(zv.w)};
        ((float4*)(vl+p*132))[dq]=gv; }
    __syncthreads();
    int og=(tid&15)*4, pg=(tid>>4)*4;
    float acc[4][4]={};
    for (int d4=0; d4<32; d4++){
        float4 wv[4], av[4];
        #pragma unroll
        for (int j=0;j<4;j++) wv[j]=((const float4*)(Wl+(og+j)*132))[d4];
        #pragma unroll
        for (int i=0;i<4;i++) av[i]=((const float4*)(vl+(pg+i)*132))[d4];
        #pragma unroll
        for (int i=0;i<4;i++)
            #pragma unroll
            for (int j=0;j<4;j++)
                acc[i][j] += av[i].x*wv[j].x + av[i].y*wv[j].y
                           + av[i].z*wv[j].z + av[i].w*wv[j].w;
    }
    #pragma unroll
    for (int i=0;i<4;i++){
        size_t gi=(pbase+pg+i)*64+og;
        float4 r=*(const float4*)(x0+gi);
        float4 o4={acc[i][0]+r.x, acc[i][1]+r.y, acc[i][2]+r.z, acc[i][3]+r.w};
        *(float4*)(x1+gi)=o4;
    }
}

extern "C" void kernel_launch(void* const* d_in, const int* in_sizes, int n_in,
                              void* d_out, int out_size, void* d_ws, size_t ws_size,
                              hipStream_t stream){
    const float* x      = (const float*)d_in[0];
    const float* ln_g   = (const float*)d_in[1];
    const float* ln_b   = (const float*)d_in[2];
    const float* w_pw1  = (const float*)d_in[3];
    const float* w_dw   = (const float*)d_in[4];
    const float* w_pw2  = (const float*)d_in[5];
    const float* w_odw1 = (const float*)d_in[6];
    const float* w_odw2 = (const float*)d_in[7];
    const float* W_inpj = (const float*)d_in[8];
    const float* conv_w = (const float*)d_in[9];
    const float* conv_b = (const float*)d_in[10];
    const float* W_xprj = (const float*)d_in[11];
    const float* W_dt   = (const float*)d_in[12];
    const float* b_dt   = (const float*)d_in[13];
    const float* A_log  = (const float*)d_in[14];
    const float* Dvec   = (const float*)d_in[15];
    const float* W_out  = (const float*)d_in[16];
    float* out = (float*)d_out;

    char* ws = (char*)d_ws;
    const size_t SZ64  = (size_t)NPIX*64*4;    // 16 MiB
    const size_t SZ128 = (size_t)NPIX*128*4;   // 32 MiB
    float* A1 = (float*)(ws);                  // x1
    float* A2 = (float*)(ws + SZ64);           // t1 -> {E,sumdt} -> t3
    float* A3 = (float*)(ws + 2*SZ64);         // t2 -> {Bm,Cm,Hst}
    float* A4 = (float*)(ws + 3*SZ64);         // x0
    float* A5 = (float*)(ws + 4*SZ64);         // xs
    float* A6 = (float*)(ws + 4*SZ64 + SZ128); // z
    float* A7 = (float*)(ws + 4*SZ64 + 2*SZ128); // y_raw
    float* A8 = (float*)(ws + 4*SZ64 + 3*SZ128); // dtr (1 MiB)
    float* Ebuf  = A2;
    float* sumdt = (float*)((char*)A2 + (size_t)B_*NC*DI_*NST*4);
    float* Bmb = A3;
    float* Cmb = (float*)((char*)A3 + (size_t)NPIX*NST*4);
    float* Hst = (float*)((char*)A3 + (size_t)2*NPIX*NST*4);

    k_lnpw          <<<NPIX/64, 256, 0, stream>>>(x, ln_g, ln_b, w_pw1, A2);
    k_dw3<true,false><<<NPIX*64/256,256, 0, stream>>>(A2, w_dw, nullptr, A3);
    k_pw            <<<NPIX/64, 256, 0, stream>>>(A3, w_pw2, A4);
    k_inproj        <<<dim3(NPIX/64,2), 256, 0, stream>>>(A4, W_inpj, A5, A6);
    k_xproj         <<<B_*NC,   256, 0, stream>>>(A5, conv_w, conv_b, W_xprj,
                                                  A8, Bmb, Cmb);
    k_scanA         <<<B_*NC,   512, 0, stream>>>(A5, conv_w, conv_b, A8, W_dt, b_dt,
                                                  Bmb, A_log, Ebuf, sumdt);
    k_scanB         <<<32,      256, 0, stream>>>(Ebuf, sumdt, A_log, Hst);
    k_scanC         <<<B_*NC,   512, 0, stream>>>(A5, conv_w, conv_b, A8, W_dt, b_dt,
                                                  Bmb, Cmb, A_log, Hst, Dvec, A7);
    k_gate_out      <<<NPIX/64, 256, 0, stream>>>(A7, A6, W_out, A4, A1);
    k_dw3<true,false><<<NPIX*64/256,256, 0, stream>>>(A1, w_odw1, nullptr, A2);
    k_dw3<false,true><<<NPIX*64/256,256, 0, stream>>>(A2, w_odw2, A1, out);
}